// Round 6
// baseline (653.812 us; speedup 1.0000x reference)
//
#include <hip/hip_runtime.h>
#include <hip/hip_fp16.h>
#include <float.h>
#include <math.h>

#define D_IN 32
#define D_MAIN 128
#define D_BLOCK 256
#define CTX 96
#define LN_EPS 1e-5f

typedef short bf16x8 __attribute__((ext_vector_type(8)));
typedef float f32x4 __attribute__((ext_vector_type(4)));
typedef unsigned short ushort4v __attribute__((ext_vector_type(4)));

#define LDA 136   // As stride (shorts), 272B rows (16B-mult)
#define LDJ 72    // wave-private u-scratch stride (shorts), 144B rows
#define LDF 68    // As-as-float staging stride (floats); 272B rows, 2-way banks

__device__ __forceinline__ unsigned short f2bf(float x) {
  union { float f; unsigned u; } v; v.f = x;
  const unsigned r = (v.u + 0x7FFFu + ((v.u >> 16) & 1u)) >> 16;
  return (unsigned short)r;
}
__device__ __forceinline__ unsigned pk2bf(float a, float b) {
  return (unsigned)f2bf(a) | ((unsigned)f2bf(b) << 16);
}
__device__ __forceinline__ float bf2f(unsigned short x) {
  union { unsigned u; float f; } v; v.u = (unsigned)x << 16; return v.f;
}

// ---------------------------------------------------------------------------
// Pack K x N fp32 weights into MFMA fragment order (bf16):
// frag f = j*(K/32)+s ; lane l holds W[k=32s+(l>>4)*8+jj][n=16j+(l&15)]
// (identical layout serves as A-frag [n][k] or B-frag [k][n] — operand symmetric)
// ---------------------------------------------------------------------------
__global__ __launch_bounds__(256) void pack_w_kernel(
    const float* __restrict__ W, int K, int N, unsigned short* __restrict__ out)
{
  const int tid = blockIdx.x * 256 + threadIdx.x;
  const int ks = K / 32;
  const int total = (N / 16) * ks * 64;
  if (tid >= total) return;
  const int l = tid & 63, f = tid >> 6;
  const int s = f % ks, j = f / ks;
  const int kb = s * 32 + (l >> 4) * 8;
  const int n = j * 16 + (l & 15);
  unsigned short v[8];
#pragma unroll
  for (int jj = 0; jj < 8; ++jj) v[jj] = f2bf(W[(size_t)(kb + jj) * N + n]);
  ushort4v* o = (ushort4v*)(out + (size_t)tid * 8);
  ushort4v u0 = {v[0], v[1], v[2], v[3]};
  ushort4v u1 = {v[4], v[5], v[6], v[7]};
  o[0] = u0; o[1] = u1;
}

// ---------------------------------------------------------------------------
// Wave-private MFMA MLP: h (2x8 C-tiles, rows rbase..rbase+32, cols 0..128)
//   += relu(As[rows]@W1 + b1) @ W2      (zero barriers)
// ---------------------------------------------------------------------------
__device__ __forceinline__ void mlp_reg(
    f32x4 (&h)[2][8],
    const unsigned short* __restrict__ As,
    unsigned short* __restrict__ Usw,
    const unsigned short* __restrict__ W1_pk,
    const unsigned short* __restrict__ b1s,   // bf16[256] in LDS
    const unsigned short* __restrict__ W2_pk,
    int rbase, int c, int q, int lane)
{
#pragma unroll 1
  for (int jc = 0; jc < 4; ++jc) {
    f32x4 acc[4][2];
#pragma unroll
    for (int jt = 0; jt < 4; ++jt)
#pragma unroll
      for (int m = 0; m < 2; ++m) { f32x4 z = {0.f,0.f,0.f,0.f}; acc[jt][m] = z; }
#pragma unroll
    for (int s = 0; s < 4; ++s) {
      bf16x8 bsrc[2];
#pragma unroll
      for (int m = 0; m < 2; ++m)
        bsrc[m] = *(const bf16x8*)&As[(rbase + m*16 + c) * LDA + s*32 + q*8];
#pragma unroll
      for (int jt = 0; jt < 4; ++jt) {
        const bf16x8 wf = *(const bf16x8*)&W1_pk[((size_t)((jc*4+jt)*4 + s) * 64 + lane) * 8];
#pragma unroll
        for (int m = 0; m < 2; ++m)
          acc[jt][m] = __builtin_amdgcn_mfma_f32_16x16x32_bf16(wf, bsrc[m], acc[jt][m], 0, 0, 0);
      }
    }
    // bias + relu + pack; u^T C-layout: lane holds j=q*4+r (regs), m=c (lanes)
#pragma unroll
    for (int jt = 0; jt < 4; ++jt) {
      const int jb = (jc*4 + jt) * 16 + q*4;
      const float bv0 = bf2f(b1s[jb + 0]);
      const float bv1 = bf2f(b1s[jb + 1]);
      const float bv2 = bf2f(b1s[jb + 2]);
      const float bv3 = bf2f(b1s[jb + 3]);
#pragma unroll
      for (int m = 0; m < 2; ++m) {
        uint2 dd;
        dd.x = pk2bf(fmaxf(acc[jt][m][0] + bv0, 0.f), fmaxf(acc[jt][m][1] + bv1, 0.f));
        dd.y = pk2bf(fmaxf(acc[jt][m][2] + bv2, 0.f), fmaxf(acc[jt][m][3] + bv3, 0.f));
        *(uint2*)&Usw[(m*16 + c) * LDJ + jt*16 + q*4] = dd;
      }
    }
    __threadfence_block();
    // phase B: h += u @ W2 (k-chunk jc*64..+64)
#pragma unroll
    for (int kw = 0; kw < 2; ++kw) {
      bf16x8 af[2];
#pragma unroll
      for (int m = 0; m < 2; ++m)
        af[m] = *(const bf16x8*)&Usw[(m*16 + c) * LDJ + kw*32 + q*8];
#pragma unroll
      for (int nt = 0; nt < 8; ++nt) {
        const bf16x8 bw = *(const bf16x8*)&W2_pk[((size_t)(nt*8 + jc*2 + kw) * 64 + lane) * 8];
#pragma unroll
        for (int m = 0; m < 2; ++m)
          h[m][nt] = __builtin_amdgcn_mfma_f32_16x16x32_bf16(af[m], bw, h[m][nt], 0, 0, 0);
      }
    }
  }
}

// LN over register h, write normalized bf16 to As (wave-private rows).
__device__ __forceinline__ void ln_write(
    f32x4 (&h)[2][8], unsigned short* __restrict__ As,
    const float* __restrict__ g, const float* __restrict__ bv,
    int rbase, int c, int q)
{
  float mu[2][4], rs[2][4];
#pragma unroll
  for (int m = 0; m < 2; ++m)
#pragma unroll
    for (int r = 0; r < 4; ++r) {
      float s = 0.f, ss = 0.f;
#pragma unroll
      for (int nt = 0; nt < 8; ++nt) { const float v = h[m][nt][r]; s += v; ss += v * v; }
#pragma unroll
      for (int off = 1; off < 16; off <<= 1) {
        s += __shfl_xor(s, off, 64);
        ss += __shfl_xor(ss, off, 64);
      }
      const float m_ = s * (1.f / 128.f);
      mu[m][r] = m_;
      rs[m][r] = rsqrtf(ss * (1.f / 128.f) - m_ * m_ + LN_EPS);
    }
#pragma unroll
  for (int nt = 0; nt < 8; ++nt) {
    const int col = nt*16 + c;
    const float gg = g[col], bb = bv[col];
#pragma unroll
    for (int m = 0; m < 2; ++m)
#pragma unroll
      for (int r = 0; r < 4; ++r)
        As[(rbase + m*16 + q*4 + r) * LDA + col] =
            f2bf((h[m][nt][r] - mu[m][r]) * rs[m][r] * gg + bb);
  }
  __threadfence_block();
}

// ---------------------------------------------------------------------------
// Encoder: block = 128 rows, 4 waves, each wave owns 32 rows.
// Epilogue stages outputs through LDS -> fully coalesced global stores.
// ---------------------------------------------------------------------------
__global__ __launch_bounds__(256, 3) void encode_mfma(
    const float* __restrict__ xin, int nrows,
    const unsigned short* __restrict__ linW_pk, const float* __restrict__ lin_b,
    const unsigned short* __restrict__ e0W1_pk, const float* __restrict__ e0_b1,
    const unsigned short* __restrict__ e0W2_pk, const float* __restrict__ e0_b2,
    const float* __restrict__ e1_g, const float* __restrict__ e1_b,
    const unsigned short* __restrict__ e1W1_pk, const float* __restrict__ e1_b1,
    const unsigned short* __restrict__ e1W2_pk, const float* __restrict__ e1_b2,
    const float* __restrict__ mix_g, const float* __restrict__ mix_b,
    const unsigned short* __restrict__ KW_pk, const float* __restrict__ K_b,
    float* __restrict__ k_out, float* __restrict__ knorm_out,
    float* __restrict__ h_out, unsigned short* __restrict__ ckbf_out)
{
  __shared__ unsigned short As[128 * LDA];
  __shared__ unsigned short Usw[4][32 * LDJ];
  __shared__ unsigned short b1s[2][256];
  const int t = threadIdx.x, lane = t & 63, w = t >> 6;
  const int c = lane & 15, q = lane >> 4;
  const int rbase = w * 32;
  const int row0 = blockIdx.x * 128;

  for (int i = t; i < 128 * 8; i += 256) {
    const int r = i >> 3, c4 = (i & 7) * 4;
    const int gr = row0 + r;
    float4 v = make_float4(0.f, 0.f, 0.f, 0.f);
    if (gr < nrows) v = *(const float4*)&xin[(size_t)gr * D_IN + c4];
    ushort4v u = {f2bf(v.x), f2bf(v.y), f2bf(v.z), f2bf(v.w)};
    *(ushort4v*)&As[r * LDA + c4] = u;
  }
  b1s[0][t] = f2bf(e0_b1[t]);
  b1s[1][t] = f2bf(e1_b1[t]);
  __syncthreads();

  f32x4 h[2][8];
  { // input linear (K=32)
    bf16x8 a[2];
#pragma unroll
    for (int m = 0; m < 2; ++m)
      a[m] = *(const bf16x8*)&As[(rbase + m*16 + c) * LDA + q*8];
#pragma unroll
    for (int nt = 0; nt < 8; ++nt) {
      const bf16x8 bw = *(const bf16x8*)&linW_pk[((size_t)nt * 64 + lane) * 8];
      const float bb = lin_b[nt*16 + c];
#pragma unroll
      for (int m = 0; m < 2; ++m) {
        f32x4 z = {0.f, 0.f, 0.f, 0.f};
        z = __builtin_amdgcn_mfma_f32_16x16x32_bf16(a[m], bw, z, 0, 0, 0);
        z[0] += bb; z[1] += bb; z[2] += bb; z[3] += bb;
        h[m][nt] = z;
      }
    }
  }
  // h -> As (e0 input), wave-private rows
#pragma unroll
  for (int nt = 0; nt < 8; ++nt)
#pragma unroll
    for (int m = 0; m < 2; ++m)
#pragma unroll
      for (int r = 0; r < 4; ++r)
        As[(rbase + m*16 + q*4 + r) * LDA + nt*16 + c] = f2bf(h[m][nt][r]);
  __threadfence_block();

  mlp_reg(h, As, Usw[w], e0W1_pk, b1s[0], e0W2_pk, rbase, c, q, lane);
#pragma unroll
  for (int nt = 0; nt < 8; ++nt) {
    const float bb = e0_b2[nt*16 + c];
#pragma unroll
    for (int m = 0; m < 2; ++m) {
      h[m][nt][0] += bb; h[m][nt][1] += bb; h[m][nt][2] += bb; h[m][nt][3] += bb;
    }
  }

  ln_write(h, As, e1_g, e1_b, rbase, c, q);
  mlp_reg(h, As, Usw[w], e1W1_pk, b1s[1], e1W2_pk, rbase, c, q, lane);
#pragma unroll
  for (int nt = 0; nt < 8; ++nt) {
    const float bb = e1_b2[nt*16 + c];
#pragma unroll
    for (int m = 0; m < 2; ++m) {
      h[m][nt][0] += bb; h[m][nt][1] += bb; h[m][nt][2] += bb; h[m][nt][3] += bb;
    }
  }

  ln_write(h, As, mix_g, mix_b, rbase, c, q);

  // K projection
  f32x4 kk[2][8];
#pragma unroll
  for (int m = 0; m < 2; ++m)
#pragma unroll
    for (int nt = 0; nt < 8; ++nt) { f32x4 z = {0.f,0.f,0.f,0.f}; kk[m][nt] = z; }
#pragma unroll
  for (int s = 0; s < 4; ++s) {
    bf16x8 a[2];
#pragma unroll
    for (int m = 0; m < 2; ++m)
      a[m] = *(const bf16x8*)&As[(rbase + m*16 + c) * LDA + s*32 + q*8];
#pragma unroll
    for (int nt = 0; nt < 8; ++nt) {
      const bf16x8 bw = *(const bf16x8*)&KW_pk[((size_t)(nt*4 + s) * 64 + lane) * 8];
#pragma unroll
      for (int m = 0; m < 2; ++m)
        kk[m][nt] = __builtin_amdgcn_mfma_f32_16x16x32_bf16(a[m], bw, kk[m][nt], 0, 0, 0);
    }
  }
#pragma unroll
  for (int nt = 0; nt < 8; ++nt) {
    const float bb = K_b[nt*16 + c];
#pragma unroll
    for (int m = 0; m < 2; ++m) {
      kk[m][nt][0] += bb; kk[m][nt][1] += bb; kk[m][nt][2] += bb; kk[m][nt][3] += bb;
    }
  }

  // knorm (per-row, shuffle-reduced; tiny scattered store)
  if (knorm_out) {
#pragma unroll
    for (int m = 0; m < 2; ++m)
#pragma unroll
      for (int r = 0; r < 4; ++r) {
        float ss = 0.f;
#pragma unroll
        for (int nt = 0; nt < 8; ++nt) { const float v = kk[m][nt][r]; ss += v * v; }
#pragma unroll
        for (int off = 1; off < 16; off <<= 1) ss += __shfl_xor(ss, off, 64);
        const int gr = row0 + rbase + m*16 + q*4 + r;
        if (c == 0 && gr < nrows) knorm_out[gr] = ss;
      }
  }

  // ---- coalesced staged stores (As reused as 128 x LDF float buffer) ----
  float* Asf = (float*)As;
#pragma unroll 1
  for (int p = 0; p < 2; ++p) {
    __syncthreads();
#pragma unroll
    for (int j = 0; j < 4; ++j) {
      const int nt = p*4 + j;
#pragma unroll
      for (int m = 0; m < 2; ++m)
#pragma unroll
        for (int r = 0; r < 4; ++r)
          Asf[(rbase + m*16 + q*4 + r) * LDF + j*16 + c] = kk[m][nt][r];
    }
    __syncthreads();
    for (int i = t; i < 128 * 16; i += 256) {
      const int row = i >> 4, fc = (i & 15) * 4;
      const int gr = row0 + row;
      if (gr < nrows) {
        const float4 v = *(const float4*)&Asf[row * LDF + fc];
        *(float4*)&k_out[(size_t)gr * D_MAIN + p*64 + fc] = v;
        if (ckbf_out) {
          ushort4v u = {f2bf(v.x), f2bf(v.y), f2bf(v.z), f2bf(v.w)};
          *(ushort4v*)&ckbf_out[(size_t)gr * D_MAIN + p*64 + fc] = u;
        }
      }
    }
  }
  if (h_out) {
#pragma unroll 1
    for (int p = 0; p < 2; ++p) {
      __syncthreads();
#pragma unroll
      for (int j = 0; j < 4; ++j) {
        const int nt = p*4 + j;
#pragma unroll
        for (int m = 0; m < 2; ++m)
#pragma unroll
          for (int r = 0; r < 4; ++r)
            Asf[(rbase + m*16 + q*4 + r) * LDF + j*16 + c] = h[m][nt][r];
      }
      __syncthreads();
      for (int i = t; i < 128 * 16; i += 256) {
        const int row = i >> 4, fc = (i & 15) * 4;
        const int gr = row0 + row;
        if (gr < nrows)
          *(float4*)&h_out[(size_t)gr * D_MAIN + p*64 + fc] =
              *(const float4*)&Asf[row * LDF + fc];
      }
    }
  }
}

// ---------------------------------------------------------------------------
// Score: S[b][j] = 2*dot(xk[b], ck[j]) - ||ck[j]||^2, fp16.
// ---------------------------------------------------------------------------
__global__ __launch_bounds__(256) void score_mfma(
    const float* __restrict__ xk, const unsigned short* __restrict__ ckbf,
    const float* __restrict__ cknorm, int N, int Npad,
    __half* __restrict__ S)
{
  __shared__ unsigned short Ks[64 * 136];
  const int t = threadIdx.x, lane = t & 63, w = t >> 6;
  const int c = lane & 15, q = lane >> 4;
  const int b0 = blockIdx.y * 64;
  const int n0 = blockIdx.x * 256 + w * 64;

  for (int i = t; i < 64 * 32; i += 256) {
    const int r = i >> 5, c4 = (i & 31) * 4;
    const float4 v = *(const float4*)&xk[(size_t)(b0 + r) * D_MAIN + c4];
    ushort4v u = {f2bf(v.x), f2bf(v.y), f2bf(v.z), f2bf(v.w)};
    *(ushort4v*)&Ks[r * 136 + c4] = u;
  }
  __syncthreads();

  f32x4 acc[4][4];
#pragma unroll
  for (int mi = 0; mi < 4; ++mi)
#pragma unroll
    for (int nt = 0; nt < 4; ++nt) { f32x4 z = {0.f,0.f,0.f,0.f}; acc[mi][nt] = z; }

#pragma unroll 1
  for (int s = 0; s < 4; ++s) {
    bf16x8 a[4];
#pragma unroll
    for (int mi = 0; mi < 4; ++mi)
      a[mi] = *(const bf16x8*)&Ks[(mi*16 + c) * 136 + s*32 + q*8];
#pragma unroll
    for (int nt = 0; nt < 4; ++nt) {
      const size_t n = (size_t)(n0 + nt*16 + c);
      const bf16x8 b = *(const bf16x8*)&ckbf[n * D_MAIN + s*32 + q*8];
#pragma unroll
      for (int mi = 0; mi < 4; ++mi)
        acc[mi][nt] = __builtin_amdgcn_mfma_f32_16x16x32_bf16(a[mi], b, acc[mi][nt], 0, 0, 0);
    }
  }
#pragma unroll
  for (int nt = 0; nt < 4; ++nt) {
    const int col = n0 + nt*16 + c;
    const float cn = (col < N) ? cknorm[col] : 0.f;
#pragma unroll
    for (int mi = 0; mi < 4; ++mi)
#pragma unroll
      for (int r = 0; r < 4; ++r) {
        const int row = b0 + mi*16 + q*4 + r;
        const float sv = (col < N) ? (2.f * acc[mi][nt][r] - cn) : -65504.f;
        S[(size_t)row * Npad + col] = __float2half(sv);
      }
  }
}

// ---------------------------------------------------------------------------
// Parallel radix-threshold top-K.
// ---------------------------------------------------------------------------
#define TK_CHUNK 4096
#define TK_RBINS 4096
#define TK_SCAP 2048

__global__ __launch_bounds__(256) void zero_int_kernel(int* __restrict__ p, int n)
{
  const int i = blockIdx.x * 256 + threadIdx.x;
  if (i < n) p[i] = 0;
}

__device__ __forceinline__ unsigned flip2(unsigned u) {
  const unsigned m = (u >> 15) & 0x00010001u;
  const unsigned xm = (m * 0xFFFFu) | ((m ^ 0x00010001u) * 0x8000u);
  return u ^ xm;
}

__global__ __launch_bounds__(256) void thist_kernel(
    const __half* __restrict__ S, int Npad, int* __restrict__ ghist)
{
  __shared__ int lh[TK_RBINS];
  const int t = threadIdx.x;
  const int row = blockIdx.y;
  const int c0 = blockIdx.x * TK_CHUNK;
  for (int i = t; i < TK_RBINS; i += 256) lh[i] = 0;
  __syncthreads();
  const unsigned* rp = (const unsigned*)(S + (size_t)row * Npad);
#pragma unroll
  for (int half = 0; half < 2; ++half) {
    const int j = c0 + half * 2048 + t * 8;
    if (j < Npad) {
      const uint4 v = *(const uint4*)(rp + (j >> 1));
      const unsigned k0 = flip2(v.x), k1 = flip2(v.y);
      const unsigned k2 = flip2(v.z), k3 = flip2(v.w);
      atomicAdd(&lh[(k0 & 0xFFFFu) >> 4], 1); atomicAdd(&lh[k0 >> 20], 1);
      atomicAdd(&lh[(k1 & 0xFFFFu) >> 4], 1); atomicAdd(&lh[k1 >> 20], 1);
      atomicAdd(&lh[(k2 & 0xFFFFu) >> 4], 1); atomicAdd(&lh[k2 >> 20], 1);
      atomicAdd(&lh[(k3 & 0xFFFFu) >> 4], 1); atomicAdd(&lh[k3 >> 20], 1);
    }
  }
  __syncthreads();
  int* gh = ghist + (size_t)row * TK_RBINS;
  for (int i = t; i < TK_RBINS; i += 256) {
    const int v = lh[i];
    if (v) atomicAdd(&gh[i], v);
  }
}

__global__ __launch_bounds__(256) void tthresh_kernel(
    const int* __restrict__ ghist, int* __restrict__ thr)
{
  __shared__ int sp[257];
  const int t = threadIdx.x;
  const int row = blockIdx.x;
  const int* gh = ghist + (size_t)row * TK_RBINS;
  int s = 0;
#pragma unroll
  for (int i = 0; i < 16; ++i) s += gh[t * 16 + i];
  sp[t] = s;
  if (t == 0) sp[256] = 0;
  __syncthreads();
  for (int off = 1; off < 256; off <<= 1) {
    const int v = (t + off < 256) ? sp[t + off] : 0;
    __syncthreads();
    sp[t] += v;
    __syncthreads();
  }
  if (sp[t] >= CTX && (t == 255 || sp[t + 1] < CTX)) {
    int running = (t == 255) ? 0 : sp[t + 1];
    int T = t * 16;
    for (int b = t * 16 + 15; b >= t * 16; --b) {
      running += gh[b];
      if (running >= CTX) { T = b; break; }
    }
    thr[row] = T;
  }
}

__global__ __launch_bounds__(256) void tcollect_kernel(
    const __half* __restrict__ S, int Npad, const int* __restrict__ thr,
    int* __restrict__ scount, unsigned long long* __restrict__ surv)
{
  const int t = threadIdx.x;
  const int row = blockIdx.y;
  const int c0 = blockIdx.x * TK_CHUNK;
  const int T = thr[row];
  const unsigned* rp = (const unsigned*)(S + (size_t)row * Npad);
  unsigned long long* sv = surv + (size_t)row * TK_SCAP;
#pragma unroll
  for (int half = 0; half < 2; ++half) {
    const int j = c0 + half * 2048 + t * 8;
    if (j < Npad) {
      const uint4 v = *(const uint4*)(rp + (j >> 1));
      unsigned ks[4] = {flip2(v.x), flip2(v.y), flip2(v.z), flip2(v.w)};
#pragma unroll
      for (int wqi = 0; wqi < 4; ++wqi) {
        const unsigned klo = ks[wqi] & 0xFFFFu;
        const unsigned khi = ks[wqi] >> 16;
        const int jlo = j + wqi * 2, jhi = j + wqi * 2 + 1;
        if ((int)(klo >> 4) >= T) {
          const int pos = atomicAdd(&scount[row], 1);
          if (pos < TK_SCAP)
            sv[pos] = ((unsigned long long)klo << 32) | (0xFFFFFFFFu - (unsigned)jlo);
        }
        if ((int)(khi >> 4) >= T) {
          const int pos = atomicAdd(&scount[row], 1);
          if (pos < TK_SCAP)
            sv[pos] = ((unsigned long long)khi << 32) | (0xFFFFFFFFu - (unsigned)jhi);
        }
      }
    }
  }
}

__global__ __launch_bounds__(1024) void tsort_kernel(
    const unsigned long long* __restrict__ surv, const int* __restrict__ scount,
    int* __restrict__ idx_out)
{
  __shared__ unsigned long long sb[TK_SCAP];
  const int t = threadIdx.x;
  const int row = blockIdx.x;
  const int m = min(scount[row], TK_SCAP);
  int L = 128;
  while (L < m) L <<= 1;           // adaptive sort length (m >= CTX guaranteed)
  const unsigned long long* sv = surv + (size_t)row * TK_SCAP;
  for (int i = t; i < L; i += 1024)
    sb[i] = (i < m) ? sv[i] : 0x00000000FFFFFFFFull;
  __syncthreads();
  for (int k = 2; k <= L; k <<= 1) {
    for (int j = k >> 1; j > 0; j >>= 1) {
      for (int i = t; i < L; i += 1024) {
        const int ixj = i ^ j;
        if (ixj > i) {
          const unsigned long long a = sb[i], b = sb[ixj];
          const bool desc = ((i & k) == 0);
          if ((a < b) == desc) { sb[i] = b; sb[ixj] = a; }
        }
      }
      __syncthreads();
    }
  }
  if (t < CTX)
    idx_out[row * CTX + t] = (int)(0xFFFFFFFFu - (unsigned)(sb[t] & 0xFFFFFFFFu));
}

// ---------------------------------------------------------------------------
// T-module + predictor + head. One block per query, 4 waves, mlp_reg MLP.
// ---------------------------------------------------------------------------
__global__ __launch_bounds__(256, 2) void tmod_kernel(
    const float* __restrict__ xh, const float* __restrict__ xk,
    const float* __restrict__ ck, const float* __restrict__ cand_y,
    const int* __restrict__ ctx_idx,
    const unsigned short* __restrict__ TW1_pk, const float* __restrict__ T_b1,
    const unsigned short* __restrict__ TW2_pk,
    const float* __restrict__ lab_w, const float* __restrict__ lab_b,
    const float* __restrict__ p0_g, const float* __restrict__ p0_b,
    const float* __restrict__ p0_W1, const float* __restrict__ p0_b1,
    const float* __restrict__ p0_W2, const float* __restrict__ p0_b2,
    const float* __restrict__ head_g, const float* __restrict__ head_b,
    const float* __restrict__ head_W, const float* __restrict__ head_bias,
    float* __restrict__ out)
{
  __shared__ unsigned short As[128 * LDA];
  __shared__ unsigned short Usw[4][32 * LDJ];
  __shared__ unsigned short b1s[256];
  __shared__ float kb[128], xhs[128], probs[128], sims[128], ys[128];
  __shared__ float part[4][128];
  __shared__ int idxs[128];
  __shared__ float xr[128], dl[128], ubuf[256], vbuf[256], scal[4];
  const int t = threadIdx.x, lane = t & 63, w = t >> 6;
  const int c = lane & 15, q = lane >> 4;
  const int rbase = w * 32;
  const int b = blockIdx.x;
  float* spart = (float*)&Usw[0][0];   // [128][16] overlay, used pre-MLP only

  if (t < 128) {
    ys[t] = 0.f;
    if (t < CTX) {
      const int j = ctx_idx[b * CTX + t];
      idxs[t] = j;
      ys[t] = cand_y[j];
    }
  }
  b1s[t] = f2bf(T_b1[t]);
  if (t < 32) {
    *(float4*)&kb[t * 4] = *(const float4*)&xk[(size_t)b * D_MAIN + t * 4];
  } else if (t < 64) {
    const int i = t - 32;
    *(float4*)&xhs[i * 4] = *(const float4*)&xh[(size_t)b * D_MAIN + i * 4];
  }
  __syncthreads();

  for (int i = t; i < 128 * 16; i += 256) {
    const int r = i >> 4, seg = i & 15, c0 = seg * 8;
    if (r < CTX) {
      const float* cr = &ck[(size_t)idxs[r] * D_MAIN + c0];
      const float4 v0 = *(const float4*)cr;
      const float4 v1 = *(const float4*)(cr + 4);
      const float4 k0 = *(const float4*)&kb[c0];
      const float4 k1 = *(const float4*)&kb[c0 + 4];
      const float d0 = k0.x - v0.x, d1 = k0.y - v0.y, d2 = k0.z - v0.z, d3 = k0.w - v0.w;
      const float d4 = k1.x - v1.x, d5 = k1.y - v1.y, d6 = k1.z - v1.z, d7 = k1.w - v1.w;
      ushort4v u0 = {f2bf(d0), f2bf(d1), f2bf(d2), f2bf(d3)};
      ushort4v u1 = {f2bf(d4), f2bf(d5), f2bf(d6), f2bf(d7)};
      *(ushort4v*)&As[r * LDA + c0] = u0;
      *(ushort4v*)&As[r * LDA + c0 + 4] = u1;
      spart[r * 16 + seg] = d0*d0 + d1*d1 + d2*d2 + d3*d3 + d4*d4 + d5*d5 + d6*d6 + d7*d7;
    } else {
      ushort4v z = {0, 0, 0, 0};
      *(ushort4v*)&As[r * LDA + c0] = z;
      *(ushort4v*)&As[r * LDA + c0 + 4] = z;
    }
  }
  __syncthreads();
  if (t < 128) {
    float s = 0.f;
    if (t < CTX) {
#pragma unroll
      for (int seg = 0; seg < 16; ++seg) s += spart[t * 16 + seg];
      sims[t] = -s;
    } else {
      sims[t] = -FLT_MAX;
    }
  }
  __syncthreads();
  if (t < 64) {
    float m = fmaxf(sims[t], sims[t + 64]);
#pragma unroll
    for (int off = 32; off > 0; off >>= 1) m = fmaxf(m, __shfl_xor(m, off, 64));
    if (t == 0) scal[0] = m;
  }
  __syncthreads();
  if (t < 128) probs[t] = (t < CTX) ? __expf(sims[t] - scal[0]) : 0.f;
  __syncthreads();
  if (t < 64) {
    float s = probs[t] + probs[t + 64];
#pragma unroll
    for (int off = 32; off > 0; off >>= 1) s += __shfl_xor(s, off, 64);
    if (t == 0) scal[1] = 1.f / s;
  }
  __syncthreads();
  if (t < 128) probs[t] *= scal[1];
  __syncthreads();
  if (t < 64) {
    float sy = probs[t] * ys[t] + probs[t + 64] * ys[t + 64];
#pragma unroll
    for (int off = 32; off > 0; off >>= 1) sy += __shfl_xor(sy, off, 64);
    if (t == 0) scal[2] = sy;
  }
  __syncthreads();   // spart reads done; Usw free for mlp_reg

  f32x4 h[2][8];
#pragma unroll
  for (int m = 0; m < 2; ++m)
#pragma unroll
    for (int nt = 0; nt < 8; ++nt) { f32x4 z = {0.f,0.f,0.f,0.f}; h[m][nt] = z; }
  mlp_reg(h, As, Usw[w], TW1_pk, b1s, TW2_pk, rbase, c, q, lane);

  // ctx[col] = sum_rows probs[row] * h[row][col]
  float pr[2][4];
#pragma unroll
  for (int m = 0; m < 2; ++m)
#pragma unroll
    for (int r = 0; r < 4; ++r)
      pr[m][r] = probs[rbase + m*16 + q*4 + r];
#pragma unroll
  for (int nt = 0; nt < 8; ++nt) {
    float p = 0.f;
#pragma unroll
    for (int m = 0; m < 2; ++m)
#pragma unroll
      for (int r = 0; r < 4; ++r)
        p += pr[m][r] * h[m][nt][r];
    p += __shfl_xor(p, 16, 64);
    p += __shfl_xor(p, 32, 64);
    if (lane < 16) part[w][nt*16 + c] = p;
  }
  __syncthreads();

  if (t < 128)
    xr[t] = xhs[t] + part[0][t] + part[1][t] + part[2][t] + part[3][t]
          + scal[2] * lab_w[t] + lab_b[t];
  __syncthreads();
  if (t < 64) {
    float s = xr[t] + xr[t + 64];
    float ss = xr[t]*xr[t] + xr[t+64]*xr[t+64];
#pragma unroll
    for (int off = 32; off > 0; off >>= 1) {
      s += __shfl_xor(s, off, 64);
      ss += __shfl_xor(ss, off, 64);
    }
    if (t == 0) {
      const float mu = s * (1.f / 128.f);
      scal[0] = mu;
      scal[1] = rsqrtf(ss * (1.f / 128.f) - mu * mu + LN_EPS);
    }
  }
  __syncthreads();
  if (t < 128)
    dl[t] = (xr[t] - scal[0]) * scal[1] * p0_g[t] + p0_b[t];
  __syncthreads();
  {
    float u = 0.f;
    for (int cc = 0; cc < D_MAIN; cc += 4) {
      const float w0 = p0_W1[(cc + 0) * D_BLOCK + t];
      const float w1 = p0_W1[(cc + 1) * D_BLOCK + t];
      const float w2 = p0_W1[(cc + 2) * D_BLOCK + t];
      const float w3 = p0_W1[(cc + 3) * D_BLOCK + t];
      const float4 d4 = *(const float4*)&dl[cc];
      u += d4.x * w0 + d4.y * w1 + d4.z * w2 + d4.w * w3;
    }
    ubuf[t] = fmaxf(u + p0_b1[t], 0.f);
  }
  __syncthreads();
  {
    const int cc = t & 127;
    const int d0 = (t >> 7) * 128;
    float v = 0.f;
    for (int d = d0; d < d0 + 128; d += 4) {
      const float w0 = p0_W2[(d + 0) * D_MAIN + cc];
      const float w1 = p0_W2[(d + 1) * D_MAIN + cc];
      const float w2 = p0_W2[(d + 2) * D_MAIN + cc];
      const float w3 = p0_W2[(d + 3) * D_MAIN + cc];
      const float4 u4 = *(const float4*)&ubuf[d];
      v += u4.x * w0 + u4.y * w1 + u4.z * w2 + u4.w * w3;
    }
    vbuf[t] = v;
  }
  __syncthreads();
  if (t < 128) xr[t] += vbuf[t] + vbuf[t + 128] + p0_b2[t];
  __syncthreads();
  if (t < 64) {
    float s = xr[t] + xr[t + 64];
    float ss = xr[t]*xr[t] + xr[t+64]*xr[t+64];
#pragma unroll
    for (int off = 32; off > 0; off >>= 1) {
      s += __shfl_xor(s, off, 64);
      ss += __shfl_xor(ss, off, 64);
    }
    if (t == 0) {
      const float mu = s * (1.f / 128.f);
      scal[0] = mu;
      scal[1] = rsqrtf(ss * (1.f / 128.f) - mu * mu + LN_EPS);
    }
  }
  __syncthreads();
  if (t < 128) {
    float hv = (xr[t] - scal[0]) * scal[1] * head_g[t] + head_b[t];
    dl[t] = fmaxf(hv, 0.f) * head_W[t];
  }
  __syncthreads();
  if (t < 64) {
    float s = dl[t] + dl[t + 64];
#pragma unroll
    for (int off = 32; off > 0; off >>= 1) s += __shfl_xor(s, off, 64);
    if (t == 0) out[b] = s + head_bias[0];
  }
}

// ---------------------------------------------------------------------------
extern "C" void kernel_launch(void* const* d_in, const int* in_sizes, int n_in,
                              void* d_out, int out_size, void* d_ws, size_t ws_size,
                              hipStream_t stream)
{
  const float* x_num   = (const float*)d_in[0];
  const float* cand_x  = (const float*)d_in[1];
  const float* cand_y  = (const float*)d_in[2];
  const float* lin_W   = (const float*)d_in[4];
  const float* lin_b   = (const float*)d_in[5];
  const float* e0_W1   = (const float*)d_in[6];
  const float* e0_b1   = (const float*)d_in[7];
  const float* e0_W2   = (const float*)d_in[8];
  const float* e0_b2   = (const float*)d_in[9];
  const float* e1_g    = (const float*)d_in[10];
  const float* e1_b    = (const float*)d_in[11];
  const float* e1_W1   = (const float*)d_in[12];
  const float* e1_b1   = (const float*)d_in[13];
  const float* e1_W2   = (const float*)d_in[14];
  const float* e1_b2   = (const float*)d_in[15];
  const float* mix_g   = (const float*)d_in[16];
  const float* mix_b   = (const float*)d_in[17];
  const float* K_W     = (const float*)d_in[18];
  const float* K_b     = (const float*)d_in[19];
  const float* T_W1    = (const float*)d_in[20];
  const float* T_b1    = (const float*)d_in[21];
  const float* T_W2    = (const float*)d_in[22];
  const float* lab_w   = (const float*)d_in[23];
  const float* lab_b   = (const float*)d_in[24];
  const float* p0_g    = (const float*)d_in[25];
  const float* p0_b    = (const float*)d_in[26];
  const float* p0_W1   = (const float*)d_in[27];
  const float* p0_b1   = (const float*)d_in[28];
  const float* p0_W2   = (const float*)d_in[29];
  const float* p0_b2   = (const float*)d_in[30];
  const float* head_g  = (const float*)d_in[31];
  const float* head_b  = (const float*)d_in[32];
  const float* head_W  = (const float*)d_in[33];
  const float* head_bias = (const float*)d_in[34];
  float* out = (float*)d_out;

  const int N = in_sizes[1] / D_IN;
  const int B = in_sizes[0] / D_IN;
  const int Npad = ((N + 255) / 256) * 256;
  const int chunks = (Npad + TK_CHUNK - 1) / TK_CHUNK;

  char* p = (char*)d_ws;
  auto take = [&](size_t bytes) {
    char* q = p;
    p += (bytes + 255) & ~(size_t)255;
    return q;
  };
  unsigned short* pk_lin  = (unsigned short*)take(32  * 128 * 2);
  unsigned short* pk_e0w1 = (unsigned short*)take(128 * 256 * 2);
  unsigned short* pk_e0w2 = (unsigned short*)take(256 * 128 * 2);
  unsigned short* pk_e1w1 = (unsigned short*)take(128 * 256 * 2);
  unsigned short* pk_e1w2 = (unsigned short*)take(256 * 128 * 2);
  unsigned short* pk_kw   = (unsigned short*)take(128 * 128 * 2);
  unsigned short* pk_tw1  = (unsigned short*)take(128 * 256 * 2);
  unsigned short* pk_tw2  = (unsigned short*)take(256 * 128 * 2);
  float*  ck      = (float*)take((size_t)Npad * D_MAIN * sizeof(float));
  unsigned short* ckbf = (unsigned short*)take((size_t)Npad * D_MAIN * sizeof(unsigned short));
  float*  cknorm  = (float*)take((size_t)N * sizeof(float));
  float*  xh      = (float*)take((size_t)B * D_MAIN * sizeof(float));
  float*  xk      = (float*)take((size_t)B * D_MAIN * sizeof(float));
  __half* S       = (__half*)take((size_t)B * Npad * sizeof(__half));
  int*    ctxidx  = (int*)take((size_t)B * CTX * sizeof(int));
  int*    ghist   = (int*)take((size_t)B * TK_RBINS * sizeof(int));
  int*    thr     = (int*)take((size_t)B * sizeof(int));
  int*    scount  = (int*)take((size_t)B * sizeof(int));
  unsigned long long* surv =
      (unsigned long long*)take((size_t)B * TK_SCAP * sizeof(unsigned long long));
  (void)ws_size; (void)n_in; (void)out_size;

  auto packW = [&](const float* W, int K, int Nn, unsigned short* o) {
    const int total = (Nn / 16) * (K / 32) * 64;
    pack_w_kernel<<<(total + 255) / 256, 256, 0, stream>>>(W, K, Nn, o);
  };
  packW(lin_W, 32, 128, pk_lin);
  packW(e0_W1, 128, 256, pk_e0w1);
  packW(e0_W2, 256, 128, pk_e0w2);
  packW(e1_W1, 128, 256, pk_e1w1);
  packW(e1_W2, 256, 128, pk_e1w2);
  packW(K_W, 128, 128, pk_kw);
  packW(T_W1, 128, 256, pk_tw1);
  packW(T_W2, 256, 128, pk_tw2);

  {
    const int nz1 = B * TK_RBINS;
    zero_int_kernel<<<(nz1 + 255) / 256, 256, 0, stream>>>(ghist, nz1);
    zero_int_kernel<<<1, 256, 0, stream>>>(scount, B);
  }

  const int encC = (N + 127) / 128;
  encode_mfma<<<encC, 256, 0, stream>>>(
      cand_x, N, pk_lin, lin_b, pk_e0w1, e0_b1, pk_e0w2, e0_b2,
      e1_g, e1_b, pk_e1w1, e1_b1, pk_e1w2, e1_b2,
      mix_g, mix_b, pk_kw, K_b, ck, cknorm, nullptr, ckbf);

  const int encB = (B + 127) / 128;
  encode_mfma<<<encB, 256, 0, stream>>>(
      x_num, B, pk_lin, lin_b, pk_e0w1, e0_b1, pk_e0w2, e0_b2,
      e1_g, e1_b, pk_e1w1, e1_b1, pk_e1w2, e1_b2,
      mix_g, mix_b, pk_kw, K_b, xk, nullptr, xh, nullptr);

  dim3 sg(Npad / 256, B / 64);
  score_mfma<<<sg, 256, 0, stream>>>(xk, ckbf, cknorm, N, Npad, S);

  dim3 tg(chunks, B);
  thist_kernel<<<tg, 256, 0, stream>>>(S, Npad, ghist);
  tthresh_kernel<<<B, 256, 0, stream>>>(ghist, thr);
  tcollect_kernel<<<tg, 256, 0, stream>>>(S, Npad, thr, scount, surv);
  tsort_kernel<<<B, 1024, 0, stream>>>(surv, scount, ctxidx);

  tmod_kernel<<<B, 256, 0, stream>>>(
      xh, xk, ck, cand_y, ctxidx,
      pk_tw1, T_b1, pk_tw2, lab_w, lab_b,
      p0_g, p0_b, p0_W1, p0_b1, p0_W2, p0_b2,
      head_g, head_b, head_W, head_bias, out);
}

// Round 8
// 568.715 us; speedup vs baseline: 1.1496x; 1.1496x over previous
//
#include <hip/hip_runtime.h>
#include <hip/hip_fp16.h>
#include <float.h>
#include <math.h>

#define D_IN 32
#define D_MAIN 128
#define D_BLOCK 256
#define CTX 96
#define LN_EPS 1e-5f

typedef short bf16x8 __attribute__((ext_vector_type(8)));
typedef float f32x4 __attribute__((ext_vector_type(4)));
typedef unsigned short ushort4v __attribute__((ext_vector_type(4)));

#define LDA 136   // As stride (shorts), 272B rows (16B-mult); = 68 floats
#define LDJ 72    // wave-private u-scratch stride (shorts)
#define LDF 68    // As-as-float stride (floats) == LDA/2

__device__ __forceinline__ unsigned short f2bf(float x) {
  union { float f; unsigned u; } v; v.f = x;
  const unsigned r = (v.u + 0x7FFFu + ((v.u >> 16) & 1u)) >> 16;
  return (unsigned short)r;
}
__device__ __forceinline__ unsigned pk2bf(float a, float b) {
  return (unsigned)f2bf(a) | ((unsigned)f2bf(b) << 16);
}
__device__ __forceinline__ float bf2f(unsigned short x) {
  union { unsigned u; float f; } v; v.u = (unsigned)x << 16; return v.f;
}

// ---------------------------------------------------------------------------
// Pack K x N fp32 weights into MFMA fragment order (bf16). Operand-symmetric:
// serves as A-frag [n][k] or B-frag [k][n].
// ---------------------------------------------------------------------------
__global__ __launch_bounds__(256) void pack_w_kernel(
    const float* __restrict__ W, int K, int N, unsigned short* __restrict__ out)
{
  const int tid = blockIdx.x * 256 + threadIdx.x;
  const int ks = K / 32;
  const int total = (N / 16) * ks * 64;
  if (tid >= total) return;
  const int l = tid & 63, f = tid >> 6;
  const int s = f % ks, j = f / ks;
  const int kb = s * 32 + (l >> 4) * 8;
  const int n = j * 16 + (l & 15);
  unsigned short v[8];
#pragma unroll
  for (int jj = 0; jj < 8; ++jj) v[jj] = f2bf(W[(size_t)(kb + jj) * N + n]);
  ushort4v* o = (ushort4v*)(out + (size_t)tid * 8);
  ushort4v u0 = {v[0], v[1], v[2], v[3]};
  ushort4v u1 = {v[4], v[5], v[6], v[7]};
  o[0] = u0; o[1] = u1;
}

// ---------------------------------------------------------------------------
// Wave-private MFMA MLP: h (2x8 C-tiles, rows rbase..rbase+32, cols 0..128)
//   += relu(As[rows]@W1 + b1) @ W2      (zero barriers)
// ---------------------------------------------------------------------------
__device__ __forceinline__ void mlp_reg(
    f32x4 (&h)[2][8],
    const unsigned short* __restrict__ As,
    unsigned short* __restrict__ Usw,
    const unsigned short* __restrict__ W1_pk,
    const unsigned short* __restrict__ b1s,   // bf16[256] in LDS
    const unsigned short* __restrict__ W2_pk,
    int rbase, int c, int q, int lane)
{
#pragma unroll 1
  for (int jc = 0; jc < 4; ++jc) {
    f32x4 acc[4][2];
#pragma unroll
    for (int jt = 0; jt < 4; ++jt)
#pragma unroll
      for (int m = 0; m < 2; ++m) { f32x4 z = {0.f,0.f,0.f,0.f}; acc[jt][m] = z; }
#pragma unroll
    for (int s = 0; s < 4; ++s) {
      bf16x8 bsrc[2];
#pragma unroll
      for (int m = 0; m < 2; ++m)
        bsrc[m] = *(const bf16x8*)&As[(rbase + m*16 + c) * LDA + s*32 + q*8];
#pragma unroll
      for (int jt = 0; jt < 4; ++jt) {
        const bf16x8 wf = *(const bf16x8*)&W1_pk[((size_t)((jc*4+jt)*4 + s) * 64 + lane) * 8];
#pragma unroll
        for (int m = 0; m < 2; ++m)
          acc[jt][m] = __builtin_amdgcn_mfma_f32_16x16x32_bf16(wf, bsrc[m], acc[jt][m], 0, 0, 0);
      }
    }
    // bias + relu + pack; u^T C-layout: lane holds j=q*4+r (regs), row=c (lanes)
#pragma unroll
    for (int jt = 0; jt < 4; ++jt) {
      const int jb = (jc*4 + jt) * 16 + q*4;
      const float bv0 = bf2f(b1s[jb + 0]);
      const float bv1 = bf2f(b1s[jb + 1]);
      const float bv2 = bf2f(b1s[jb + 2]);
      const float bv3 = bf2f(b1s[jb + 3]);
#pragma unroll
      for (int m = 0; m < 2; ++m) {
        uint2 dd;
        dd.x = pk2bf(fmaxf(acc[jt][m][0] + bv0, 0.f), fmaxf(acc[jt][m][1] + bv1, 0.f));
        dd.y = pk2bf(fmaxf(acc[jt][m][2] + bv2, 0.f), fmaxf(acc[jt][m][3] + bv3, 0.f));
        *(uint2*)&Usw[(m*16 + c) * LDJ + jt*16 + q*4] = dd;
      }
    }
    __threadfence_block();
    // phase B: h += u @ W2 (k-chunk jc*64..+64)
#pragma unroll
    for (int kw = 0; kw < 2; ++kw) {
      bf16x8 af[2];
#pragma unroll
      for (int m = 0; m < 2; ++m)
        af[m] = *(const bf16x8*)&Usw[(m*16 + c) * LDJ + kw*32 + q*8];
#pragma unroll
      for (int nt = 0; nt < 8; ++nt) {
        const bf16x8 bw = *(const bf16x8*)&W2_pk[((size_t)(nt*8 + jc*2 + kw) * 64 + lane) * 8];
#pragma unroll
        for (int m = 0; m < 2; ++m)
          h[m][nt] = __builtin_amdgcn_mfma_f32_16x16x32_bf16(af[m], bw, h[m][nt], 0, 0, 0);
      }
    }
  }
}

// LN over register h, write normalized bf16 to As (wave-private rows).
__device__ __forceinline__ void ln_write(
    f32x4 (&h)[2][8], unsigned short* __restrict__ As,
    const float* __restrict__ g, const float* __restrict__ bv,
    int rbase, int c, int q)
{
  float mu[2][4], rs[2][4];
#pragma unroll
  for (int m = 0; m < 2; ++m)
#pragma unroll
    for (int r = 0; r < 4; ++r) {
      float s = 0.f, ss = 0.f;
#pragma unroll
      for (int nt = 0; nt < 8; ++nt) { const float v = h[m][nt][r]; s += v; ss += v * v; }
#pragma unroll
      for (int off = 1; off < 16; off <<= 1) {
        s += __shfl_xor(s, off, 64);
        ss += __shfl_xor(ss, off, 64);
      }
      const float m_ = s * (1.f / 128.f);
      mu[m][r] = m_;
      rs[m][r] = rsqrtf(ss * (1.f / 128.f) - m_ * m_ + LN_EPS);
    }
#pragma unroll
  for (int nt = 0; nt < 8; ++nt) {
    const int col = nt*16 + c;
    const float gg = g[col], bb = bv[col];
#pragma unroll
    for (int m = 0; m < 2; ++m)
#pragma unroll
      for (int r = 0; r < 4; ++r)
        As[(rbase + m*16 + q*4 + r) * LDA + col] =
            f2bf((h[m][nt][r] - mu[m][r]) * rs[m][r] * gg + bb);
  }
  __threadfence_block();
}

// ---------------------------------------------------------------------------
// Encoder: block = 128 rows, 4 waves, each wave owns 32 rows.
// QUERY=false: h dead after mix-LN (low pressure, 3 blk/CU); wave-private
//   two-pass staged coalesced stores of k (f32) + k (bf16).
// QUERY=true: keeps h, per-element stores, 2 blk/CU (tiny grid).
// ---------------------------------------------------------------------------
template<bool QUERY>
__global__ __launch_bounds__(256, QUERY ? 2 : 3) void encode_mfma(
    const float* __restrict__ xin, int nrows,
    const unsigned short* __restrict__ linW_pk, const float* __restrict__ lin_b,
    const unsigned short* __restrict__ e0W1_pk, const float* __restrict__ e0_b1,
    const unsigned short* __restrict__ e0W2_pk, const float* __restrict__ e0_b2,
    const float* __restrict__ e1_g, const float* __restrict__ e1_b,
    const unsigned short* __restrict__ e1W1_pk, const float* __restrict__ e1_b1,
    const unsigned short* __restrict__ e1W2_pk, const float* __restrict__ e1_b2,
    const float* __restrict__ mix_g, const float* __restrict__ mix_b,
    const unsigned short* __restrict__ KW_pk, const float* __restrict__ K_b,
    float* __restrict__ k_out, float* __restrict__ knorm_out,
    float* __restrict__ h_out, unsigned short* __restrict__ ckbf_out)
{
  __shared__ unsigned short As[128 * LDA];
  __shared__ unsigned short Usw[4][32 * LDJ];
  __shared__ unsigned short b1s[2][256];
  const int t = threadIdx.x, lane = t & 63, w = t >> 6;
  const int c = lane & 15, q = lane >> 4;
  const int rbase = w * 32;
  const int row0 = blockIdx.x * 128;

  for (int i = t; i < 128 * 8; i += 256) {
    const int r = i >> 3, c4 = (i & 7) * 4;
    const int gr = row0 + r;
    float4 v = make_float4(0.f, 0.f, 0.f, 0.f);
    if (gr < nrows) v = *(const float4*)&xin[(size_t)gr * D_IN + c4];
    ushort4v u = {f2bf(v.x), f2bf(v.y), f2bf(v.z), f2bf(v.w)};
    *(ushort4v*)&As[r * LDA + c4] = u;
  }
  b1s[0][t] = f2bf(e0_b1[t]);
  b1s[1][t] = f2bf(e1_b1[t]);
  __syncthreads();

  f32x4 h[2][8];
  { // input linear (K=32)
    bf16x8 a[2];
#pragma unroll
    for (int m = 0; m < 2; ++m)
      a[m] = *(const bf16x8*)&As[(rbase + m*16 + c) * LDA + q*8];
#pragma unroll
    for (int nt = 0; nt < 8; ++nt) {
      const bf16x8 bw = *(const bf16x8*)&linW_pk[((size_t)nt * 64 + lane) * 8];
      const float bb = lin_b[nt*16 + c];
#pragma unroll
      for (int m = 0; m < 2; ++m) {
        f32x4 z = {0.f, 0.f, 0.f, 0.f};
        z = __builtin_amdgcn_mfma_f32_16x16x32_bf16(a[m], bw, z, 0, 0, 0);
        z[0] += bb; z[1] += bb; z[2] += bb; z[3] += bb;
        h[m][nt] = z;
      }
    }
  }
  // h -> As (e0 input), wave-private rows
#pragma unroll
  for (int nt = 0; nt < 8; ++nt)
#pragma unroll
    for (int m = 0; m < 2; ++m)
#pragma unroll
      for (int r = 0; r < 4; ++r)
        As[(rbase + m*16 + q*4 + r) * LDA + nt*16 + c] = f2bf(h[m][nt][r]);
  __threadfence_block();

  mlp_reg(h, As, Usw[w], e0W1_pk, b1s[0], e0W2_pk, rbase, c, q, lane);
#pragma unroll
  for (int nt = 0; nt < 8; ++nt) {
    const float bb = e0_b2[nt*16 + c];
#pragma unroll
    for (int m = 0; m < 2; ++m) {
      h[m][nt][0] += bb; h[m][nt][1] += bb; h[m][nt][2] += bb; h[m][nt][3] += bb;
    }
  }

  ln_write(h, As, e1_g, e1_b, rbase, c, q);
  mlp_reg(h, As, Usw[w], e1W1_pk, b1s[1], e1W2_pk, rbase, c, q, lane);
#pragma unroll
  for (int nt = 0; nt < 8; ++nt) {
    const float bb = e1_b2[nt*16 + c];
#pragma unroll
    for (int m = 0; m < 2; ++m) {
      h[m][nt][0] += bb; h[m][nt][1] += bb; h[m][nt][2] += bb; h[m][nt][3] += bb;
    }
  }

  ln_write(h, As, mix_g, mix_b, rbase, c, q);
  // From here, h is dead in the candidate path (no h_out) -> low pressure.

  // K projection
  f32x4 kk[2][8];
#pragma unroll
  for (int m = 0; m < 2; ++m)
#pragma unroll
    for (int nt = 0; nt < 8; ++nt) { f32x4 z = {0.f,0.f,0.f,0.f}; kk[m][nt] = z; }
#pragma unroll
  for (int s = 0; s < 4; ++s) {
    bf16x8 a[2];
#pragma unroll
    for (int m = 0; m < 2; ++m)
      a[m] = *(const bf16x8*)&As[(rbase + m*16 + c) * LDA + s*32 + q*8];
#pragma unroll
    for (int nt = 0; nt < 8; ++nt) {
      const bf16x8 bw = *(const bf16x8*)&KW_pk[((size_t)(nt*4 + s) * 64 + lane) * 8];
#pragma unroll
      for (int m = 0; m < 2; ++m)
        kk[m][nt] = __builtin_amdgcn_mfma_f32_16x16x32_bf16(a[m], bw, kk[m][nt], 0, 0, 0);
    }
  }
#pragma unroll
  for (int nt = 0; nt < 8; ++nt) {
    const float bb = K_b[nt*16 + c];
#pragma unroll
    for (int m = 0; m < 2; ++m) {
      kk[m][nt][0] += bb; kk[m][nt][1] += bb; kk[m][nt][2] += bb; kk[m][nt][3] += bb;
    }
  }

  if constexpr (QUERY) {
    // tiny grid: per-element stores for k and h
#pragma unroll
    for (int nt = 0; nt < 8; ++nt) {
      const int col = nt*16 + c;
#pragma unroll
      for (int m = 0; m < 2; ++m)
#pragma unroll
        for (int r = 0; r < 4; ++r) {
          const int gr = row0 + rbase + m*16 + q*4 + r;
          if (gr < nrows) {
            k_out[(size_t)gr * D_MAIN + col] = kk[m][nt][r];
            h_out[(size_t)gr * D_MAIN + col] = h[m][nt][r];
          }
        }
    }
  } else {
    // knorm (per-row, shuffle-reduced)
#pragma unroll
    for (int m = 0; m < 2; ++m)
#pragma unroll
      for (int r = 0; r < 4; ++r) {
        float ss = 0.f;
#pragma unroll
        for (int nt = 0; nt < 8; ++nt) { const float v = kk[m][nt][r]; ss += v * v; }
#pragma unroll
        for (int off = 1; off < 16; off <<= 1) ss += __shfl_xor(ss, off, 64);
        const int gr = row0 + rbase + m*16 + q*4 + r;
        if (c == 0 && gr < nrows) knorm_out[gr] = ss;
      }
    // wave-private two-pass restage (32 x 64 floats per pass in own As slice,
    // stride LDF=68) -> fully coalesced stores. No barriers (wave-private).
    float* Asf = (float*)&As[rbase * LDA];
#pragma unroll 1
    for (int p = 0; p < 2; ++p) {
      if (p) __threadfence_block();   // WAR guard: pass-0 reads vs pass-1 writes
#pragma unroll
      for (int j = 0; j < 4; ++j) {
        const int nt = p*4 + j;
#pragma unroll
        for (int m = 0; m < 2; ++m)
#pragma unroll
          for (int r = 0; r < 4; ++r)
            Asf[(m*16 + q*4 + r) * LDF + j*16 + c] = kk[m][nt][r];
      }
      __threadfence_block();
#pragma unroll
      for (int i = 0; i < 8; ++i) {
        const int flat = i * 64 + lane;     // 0..511
        const int row = flat >> 4;          // 0..31 (16 float4 per row)
        const int fc = (flat & 15) * 4;     // 0..60
        const int gr = row0 + rbase + row;
        if (gr < nrows) {
          const float4 v = *(const float4*)&Asf[row * LDF + fc];
          *(float4*)&k_out[(size_t)gr * D_MAIN + p*64 + fc] = v;
          ushort4v u = {f2bf(v.x), f2bf(v.y), f2bf(v.z), f2bf(v.w)};
          *(ushort4v*)&ckbf_out[(size_t)gr * D_MAIN + p*64 + fc] = u;
        }
      }
    }
  }
}

// ---------------------------------------------------------------------------
// Score: S[b][j] = 2*dot(xk[b], ck[j]) - ||ck[j]||^2, fp16.
// ---------------------------------------------------------------------------
__global__ __launch_bounds__(256) void score_mfma(
    const float* __restrict__ xk, const unsigned short* __restrict__ ckbf,
    const float* __restrict__ cknorm, int N, int Npad,
    __half* __restrict__ S)
{
  __shared__ unsigned short Ks[64 * 136];
  const int t = threadIdx.x, lane = t & 63, w = t >> 6;
  const int c = lane & 15, q = lane >> 4;
  const int b0 = blockIdx.y * 64;
  const int n0 = blockIdx.x * 256 + w * 64;

  for (int i = t; i < 64 * 32; i += 256) {
    const int r = i >> 5, c4 = (i & 31) * 4;
    const float4 v = *(const float4*)&xk[(size_t)(b0 + r) * D_MAIN + c4];
    ushort4v u = {f2bf(v.x), f2bf(v.y), f2bf(v.z), f2bf(v.w)};
    *(ushort4v*)&Ks[r * 136 + c4] = u;
  }
  __syncthreads();

  f32x4 acc[4][4];
#pragma unroll
  for (int mi = 0; mi < 4; ++mi)
#pragma unroll
    for (int nt = 0; nt < 4; ++nt) { f32x4 z = {0.f,0.f,0.f,0.f}; acc[mi][nt] = z; }

#pragma unroll 1
  for (int s = 0; s < 4; ++s) {
    bf16x8 a[4];
#pragma unroll
    for (int mi = 0; mi < 4; ++mi)
      a[mi] = *(const bf16x8*)&Ks[(mi*16 + c) * 136 + s*32 + q*8];
#pragma unroll
    for (int nt = 0; nt < 4; ++nt) {
      const size_t n = (size_t)(n0 + nt*16 + c);
      const bf16x8 b = *(const bf16x8*)&ckbf[n * D_MAIN + s*32 + q*8];
#pragma unroll
      for (int mi = 0; mi < 4; ++mi)
        acc[mi][nt] = __builtin_amdgcn_mfma_f32_16x16x32_bf16(a[mi], b, acc[mi][nt], 0, 0, 0);
    }
  }
#pragma unroll
  for (int nt = 0; nt < 4; ++nt) {
    const int col = n0 + nt*16 + c;
    const float cn = (col < N) ? cknorm[col] : 0.f;
#pragma unroll
    for (int mi = 0; mi < 4; ++mi)
#pragma unroll
      for (int r = 0; r < 4; ++r) {
        const int row = b0 + mi*16 + q*4 + r;
        const float sv = (col < N) ? (2.f * acc[mi][nt][r] - cn) : -65504.f;
        S[(size_t)row * Npad + col] = __float2half(sv);
      }
  }
}

// ---------------------------------------------------------------------------
// Parallel radix-threshold top-K.
// ---------------------------------------------------------------------------
#define TK_CHUNK 4096
#define TK_RBINS 4096
#define TK_SCAP 2048

__global__ __launch_bounds__(256) void zero_int_kernel(int* __restrict__ p, int n)
{
  const int i = blockIdx.x * 256 + threadIdx.x;
  if (i < n) p[i] = 0;
}

__device__ __forceinline__ unsigned flip2(unsigned u) {
  const unsigned m = (u >> 15) & 0x00010001u;
  const unsigned xm = (m * 0xFFFFu) | ((m ^ 0x00010001u) * 0x8000u);
  return u ^ xm;
}

__global__ __launch_bounds__(256) void thist_kernel(
    const __half* __restrict__ S, int Npad, int* __restrict__ ghist)
{
  __shared__ int lh[TK_RBINS];
  const int t = threadIdx.x;
  const int row = blockIdx.y;
  const int c0 = blockIdx.x * TK_CHUNK;
  for (int i = t; i < TK_RBINS; i += 256) lh[i] = 0;
  __syncthreads();
  const unsigned* rp = (const unsigned*)(S + (size_t)row * Npad);
#pragma unroll
  for (int half = 0; half < 2; ++half) {
    const int j = c0 + half * 2048 + t * 8;
    if (j < Npad) {
      const uint4 v = *(const uint4*)(rp + (j >> 1));
      const unsigned k0 = flip2(v.x), k1 = flip2(v.y);
      const unsigned k2 = flip2(v.z), k3 = flip2(v.w);
      atomicAdd(&lh[(k0 & 0xFFFFu) >> 4], 1); atomicAdd(&lh[k0 >> 20], 1);
      atomicAdd(&lh[(k1 & 0xFFFFu) >> 4], 1); atomicAdd(&lh[k1 >> 20], 1);
      atomicAdd(&lh[(k2 & 0xFFFFu) >> 4], 1); atomicAdd(&lh[k2 >> 20], 1);
      atomicAdd(&lh[(k3 & 0xFFFFu) >> 4], 1); atomicAdd(&lh[k3 >> 20], 1);
    }
  }
  __syncthreads();
  int* gh = ghist + (size_t)row * TK_RBINS;
  for (int i = t; i < TK_RBINS; i += 256) {
    const int v = lh[i];
    if (v) atomicAdd(&gh[i], v);
  }
}

__global__ __launch_bounds__(256) void tthresh_kernel(
    const int* __restrict__ ghist, int* __restrict__ thr)
{
  __shared__ int sp[257];
  const int t = threadIdx.x;
  const int row = blockIdx.x;
  const int* gh = ghist + (size_t)row * TK_RBINS;
  int s = 0;
#pragma unroll
  for (int i = 0; i < 16; ++i) s += gh[t * 16 + i];
  sp[t] = s;
  if (t == 0) sp[256] = 0;
  __syncthreads();
  for (int off = 1; off < 256; off <<= 1) {
    const int v = (t + off < 256) ? sp[t + off] : 0;
    __syncthreads();
    sp[t] += v;
    __syncthreads();
  }
  if (sp[t] >= CTX && (t == 255 || sp[t + 1] < CTX)) {
    int running = (t == 255) ? 0 : sp[t + 1];
    int T = t * 16;
    for (int b = t * 16 + 15; b >= t * 16; --b) {
      running += gh[b];
      if (running >= CTX) { T = b; break; }
    }
    thr[row] = T;
  }
}

__global__ __launch_bounds__(256) void tcollect_kernel(
    const __half* __restrict__ S, int Npad, const int* __restrict__ thr,
    int* __restrict__ scount, unsigned long long* __restrict__ surv)
{
  const int t = threadIdx.x;
  const int row = blockIdx.y;
  const int c0 = blockIdx.x * TK_CHUNK;
  const int T = thr[row];
  const unsigned* rp = (const unsigned*)(S + (size_t)row * Npad);
  unsigned long long* sv = surv + (size_t)row * TK_SCAP;
#pragma unroll
  for (int half = 0; half < 2; ++half) {
    const int j = c0 + half * 2048 + t * 8;
    if (j < Npad) {
      const uint4 v = *(const uint4*)(rp + (j >> 1));
      unsigned ks[4] = {flip2(v.x), flip2(v.y), flip2(v.z), flip2(v.w)};
#pragma unroll
      for (int wqi = 0; wqi < 4; ++wqi) {
        const unsigned klo = ks[wqi] & 0xFFFFu;
        const unsigned khi = ks[wqi] >> 16;
        const int jlo = j + wqi * 2, jhi = j + wqi * 2 + 1;
        if ((int)(klo >> 4) >= T) {
          const int pos = atomicAdd(&scount[row], 1);
          if (pos < TK_SCAP)
            sv[pos] = ((unsigned long long)klo << 32) | (0xFFFFFFFFu - (unsigned)jlo);
        }
        if ((int)(khi >> 4) >= T) {
          const int pos = atomicAdd(&scount[row], 1);
          if (pos < TK_SCAP)
            sv[pos] = ((unsigned long long)khi << 32) | (0xFFFFFFFFu - (unsigned)jhi);
        }
      }
    }
  }
}

__global__ __launch_bounds__(1024) void tsort_kernel(
    const unsigned long long* __restrict__ surv, const int* __restrict__ scount,
    int* __restrict__ idx_out)
{
  __shared__ unsigned long long sb[TK_SCAP];
  const int t = threadIdx.x;
  const int row = blockIdx.x;
  const int m = min(scount[row], TK_SCAP);
  int L = 128;
  while (L < m) L <<= 1;           // adaptive sort length (m >= CTX guaranteed)
  const unsigned long long* sv = surv + (size_t)row * TK_SCAP;
  for (int i = t; i < L; i += 1024)
    sb[i] = (i < m) ? sv[i] : 0x00000000FFFFFFFFull;
  __syncthreads();
  for (int k = 2; k <= L; k <<= 1) {
    for (int j = k >> 1; j > 0; j >>= 1) {
      for (int i = t; i < L; i += 1024) {
        const int ixj = i ^ j;
        if (ixj > i) {
          const unsigned long long a = sb[i], b = sb[ixj];
          const bool desc = ((i & k) == 0);
          if ((a < b) == desc) { sb[i] = b; sb[ixj] = a; }
        }
      }
      __syncthreads();
    }
  }
  if (t < CTX)
    idx_out[row * CTX + t] = (int)(0xFFFFFFFFu - (unsigned)(sb[t] & 0xFFFFFFFFu));
}

// ---------------------------------------------------------------------------
// T-module + predictor + head. One block per query, 4 waves, mlp_reg MLP.
// ---------------------------------------------------------------------------
__global__ __launch_bounds__(256, 2) void tmod_kernel(
    const float* __restrict__ xh, const float* __restrict__ xk,
    const float* __restrict__ ck, const float* __restrict__ cand_y,
    const int* __restrict__ ctx_idx,
    const unsigned short* __restrict__ TW1_pk, const float* __restrict__ T_b1,
    const unsigned short* __restrict__ TW2_pk,
    const float* __restrict__ lab_w, const float* __restrict__ lab_b,
    const float* __restrict__ p0_g, const float* __restrict__ p0_b,
    const float* __restrict__ p0_W1, const float* __restrict__ p0_b1,
    const float* __restrict__ p0_W2, const float* __restrict__ p0_b2,
    const float* __restrict__ head_g, const float* __restrict__ head_b,
    const float* __restrict__ head_W, const float* __restrict__ head_bias,
    float* __restrict__ out)
{
  __shared__ unsigned short As[128 * LDA];
  __shared__ unsigned short Usw[4][32 * LDJ];
  __shared__ unsigned short b1s[256];
  __shared__ float kb[128], xhs[128], probs[128], sims[128], ys[128];
  __shared__ float part[4][128];
  __shared__ int idxs[128];
  __shared__ float xr[128], dl[128], ubuf[256], vbuf[256], scal[4];
  const int t = threadIdx.x, lane = t & 63, w = t >> 6;
  const int c = lane & 15, q = lane >> 4;
  const int rbase = w * 32;
  const int b = blockIdx.x;
  float* spart = (float*)&Usw[0][0];   // [128][16] overlay, used pre-MLP only

  if (t < 128) {
    ys[t] = 0.f;
    if (t < CTX) {
      const int j = ctx_idx[b * CTX + t];
      idxs[t] = j;
      ys[t] = cand_y[j];
    }
  }
  b1s[t] = f2bf(T_b1[t]);
  if (t < 32) {
    *(float4*)&kb[t * 4] = *(const float4*)&xk[(size_t)b * D_MAIN + t * 4];
  } else if (t < 64) {
    const int i = t - 32;
    *(float4*)&xhs[i * 4] = *(const float4*)&xh[(size_t)b * D_MAIN + i * 4];
  }
  __syncthreads();

  for (int i = t; i < 128 * 16; i += 256) {
    const int r = i >> 4, seg = i & 15, c0 = seg * 8;
    if (r < CTX) {
      const float* cr = &ck[(size_t)idxs[r] * D_MAIN + c0];
      const float4 v0 = *(const float4*)cr;
      const float4 v1 = *(const float4*)(cr + 4);
      const float4 k0 = *(const float4*)&kb[c0];
      const float4 k1 = *(const float4*)&kb[c0 + 4];
      const float d0 = k0.x - v0.x, d1 = k0.y - v0.y, d2 = k0.z - v0.z, d3 = k0.w - v0.w;
      const float d4 = k1.x - v1.x, d5 = k1.y - v1.y, d6 = k1.z - v1.z, d7 = k1.w - v1.w;
      ushort4v u0 = {f2bf(d0), f2bf(d1), f2bf(d2), f2bf(d3)};
      ushort4v u1 = {f2bf(d4), f2bf(d5), f2bf(d6), f2bf(d7)};
      *(ushort4v*)&As[r * LDA + c0] = u0;
      *(ushort4v*)&As[r * LDA + c0 + 4] = u1;
      spart[r * 16 + seg] = d0*d0 + d1*d1 + d2*d2 + d3*d3 + d4*d4 + d5*d5 + d6*d6 + d7*d7;
    } else {
      ushort4v z = {0, 0, 0, 0};
      *(ushort4v*)&As[r * LDA + c0] = z;
      *(ushort4v*)&As[r * LDA + c0 + 4] = z;
    }
  }
  __syncthreads();
  if (t < 128) {
    float s = 0.f;
    if (t < CTX) {
#pragma unroll
      for (int seg = 0; seg < 16; ++seg) s += spart[t * 16 + seg];
      sims[t] = -s;
    } else {
      sims[t] = -FLT_MAX;
    }
  }
  __syncthreads();
  if (t < 64) {
    float m = fmaxf(sims[t], sims[t + 64]);
#pragma unroll
    for (int off = 32; off > 0; off >>= 1) m = fmaxf(m, __shfl_xor(m, off, 64));
    if (t == 0) scal[0] = m;
  }
  __syncthreads();
  if (t < 128) probs[t] = (t < CTX) ? __expf(sims[t] - scal[0]) : 0.f;
  __syncthreads();
  if (t < 64) {
    float s = probs[t] + probs[t + 64];
#pragma unroll
    for (int off = 32; off > 0; off >>= 1) s += __shfl_xor(s, off, 64);
    if (t == 0) scal[1] = 1.f / s;
  }
  __syncthreads();
  if (t < 128) probs[t] *= scal[1];
  __syncthreads();
  if (t < 64) {
    float sy = probs[t] * ys[t] + probs[t + 64] * ys[t + 64];
#pragma unroll
    for (int off = 32; off > 0; off >>= 1) sy += __shfl_xor(sy, off, 64);
    if (t == 0) scal[2] = sy;
  }
  __syncthreads();   // spart reads done; Usw free for mlp_reg

  f32x4 h[2][8];
#pragma unroll
  for (int m = 0; m < 2; ++m)
#pragma unroll
    for (int nt = 0; nt < 8; ++nt) { f32x4 z = {0.f,0.f,0.f,0.f}; h[m][nt] = z; }
  mlp_reg(h, As, Usw[w], TW1_pk, b1s, TW2_pk, rbase, c, q, lane);

  // ctx[col] = sum_rows probs[row] * h[row][col]
  float pr[2][4];
#pragma unroll
  for (int m = 0; m < 2; ++m)
#pragma unroll
    for (int r = 0; r < 4; ++r)
      pr[m][r] = probs[rbase + m*16 + q*4 + r];
#pragma unroll
  for (int nt = 0; nt < 8; ++nt) {
    float p = 0.f;
#pragma unroll
    for (int m = 0; m < 2; ++m)
#pragma unroll
      for (int r = 0; r < 4; ++r)
        p += pr[m][r] * h[m][nt][r];
    p += __shfl_xor(p, 16, 64);
    p += __shfl_xor(p, 32, 64);
    if (lane < 16) part[w][nt*16 + c] = p;
  }
  __syncthreads();

  if (t < 128)
    xr[t] = xhs[t] + part[0][t] + part[1][t] + part[2][t] + part[3][t]
          + scal[2] * lab_w[t] + lab_b[t];
  __syncthreads();
  if (t < 64) {
    float s = xr[t] + xr[t + 64];
    float ss = xr[t]*xr[t] + xr[t+64]*xr[t+64];
#pragma unroll
    for (int off = 32; off > 0; off >>= 1) {
      s += __shfl_xor(s, off, 64);
      ss += __shfl_xor(ss, off, 64);
    }
    if (t == 0) {
      const float mu = s * (1.f / 128.f);
      scal[0] = mu;
      scal[1] = rsqrtf(ss * (1.f / 128.f) - mu * mu + LN_EPS);
    }
  }
  __syncthreads();
  if (t < 128)
    dl[t] = (xr[t] - scal[0]) * scal[1] * p0_g[t] + p0_b[t];
  __syncthreads();
  {
    float u = 0.f;
    for (int cc = 0; cc < D_MAIN; cc += 4) {
      const float w0 = p0_W1[(cc + 0) * D_BLOCK + t];
      const float w1 = p0_W1[(cc + 1) * D_BLOCK + t];
      const float w2 = p0_W1[(cc + 2) * D_BLOCK + t];
      const float w3 = p0_W1[(cc + 3) * D_BLOCK + t];
      const float4 d4 = *(const float4*)&dl[cc];
      u += d4.x * w0 + d4.y * w1 + d4.z * w2 + d4.w * w3;
    }
    ubuf[t] = fmaxf(u + p0_b1[t], 0.f);
  }
  __syncthreads();
  {
    const int cc = t & 127;
    const int d0 = (t >> 7) * 128;
    float v = 0.f;
    for (int d = d0; d < d0 + 128; d += 4) {
      const float w0 = p0_W2[(d + 0) * D_MAIN + cc];
      const float w1 = p0_W2[(d + 1) * D_MAIN + cc];
      const float w2 = p0_W2[(d + 2) * D_MAIN + cc];
      const float w3 = p0_W2[(d + 3) * D_MAIN + cc];
      const float4 u4 = *(const float4*)&ubuf[d];
      v += u4.x * w0 + u4.y * w1 + u4.z * w2 + u4.w * w3;
    }
    vbuf[t] = v;
  }
  __syncthreads();
  if (t < 128) xr[t] += vbuf[t] + vbuf[t + 128] + p0_b2[t];
  __syncthreads();
  if (t < 64) {
    float s = xr[t] + xr[t + 64];
    float ss = xr[t]*xr[t] + xr[t+64]*xr[t+64];
#pragma unroll
    for (int off = 32; off > 0; off >>= 1) {
      s += __shfl_xor(s, off, 64);
      ss += __shfl_xor(ss, off, 64);
    }
    if (t == 0) {
      const float mu = s * (1.f / 128.f);
      scal[0] = mu;
      scal[1] = rsqrtf(ss * (1.f / 128.f) - mu * mu + LN_EPS);
    }
  }
  __syncthreads();
  if (t < 128) {
    float hv = (xr[t] - scal[0]) * scal[1] * head_g[t] + head_b[t];
    dl[t] = fmaxf(hv, 0.f) * head_W[t];
  }
  __syncthreads();
  if (t < 64) {
    float s = dl[t] + dl[t + 64];
#pragma unroll
    for (int off = 32; off > 0; off >>= 1) s += __shfl_xor(s, off, 64);
    if (t == 0) out[b] = s + head_bias[0];
  }
}

// ---------------------------------------------------------------------------
extern "C" void kernel_launch(void* const* d_in, const int* in_sizes, int n_in,
                              void* d_out, int out_size, void* d_ws, size_t ws_size,
                              hipStream_t stream)
{
  const float* x_num   = (const float*)d_in[0];
  const float* cand_x  = (const float*)d_in[1];
  const float* cand_y  = (const float*)d_in[2];
  const float* lin_W   = (const float*)d_in[4];
  const float* lin_b   = (const float*)d_in[5];
  const float* e0_W1   = (const float*)d_in[6];
  const float* e0_b1   = (const float*)d_in[7];
  const float* e0_W2   = (const float*)d_in[8];
  const float* e0_b2   = (const float*)d_in[9];
  const float* e1_g    = (const float*)d_in[10];
  const float* e1_b    = (const float*)d_in[11];
  const float* e1_W1   = (const float*)d_in[12];
  const float* e1_b1   = (const float*)d_in[13];
  const float* e1_W2   = (const float*)d_in[14];
  const float* e1_b2   = (const float*)d_in[15];
  const float* mix_g   = (const float*)d_in[16];
  const float* mix_b   = (const float*)d_in[17];
  const float* K_W     = (const float*)d_in[18];
  const float* K_b     = (const float*)d_in[19];
  const float* T_W1    = (const float*)d_in[20];
  const float* T_b1    = (const float*)d_in[21];
  const float* T_W2    = (const float*)d_in[22];
  const float* lab_w   = (const float*)d_in[23];
  const float* lab_b   = (const float*)d_in[24];
  const float* p0_g    = (const float*)d_in[25];
  const float* p0_b    = (const float*)d_in[26];
  const float* p0_W1   = (const float*)d_in[27];
  const float* p0_b1   = (const float*)d_in[28];
  const float* p0_W2   = (const float*)d_in[29];
  const float* p0_b2   = (const float*)d_in[30];
  const float* head_g  = (const float*)d_in[31];
  const float* head_b  = (const float*)d_in[32];
  const float* head_W  = (const float*)d_in[33];
  const float* head_bias = (const float*)d_in[34];
  float* out = (float*)d_out;

  const int N = in_sizes[1] / D_IN;
  const int B = in_sizes[0] / D_IN;
  const int Npad = ((N + 255) / 256) * 256;
  const int chunks = (Npad + TK_CHUNK - 1) / TK_CHUNK;

  char* p = (char*)d_ws;
  auto take = [&](size_t bytes) {
    char* q = p;
    p += (bytes + 255) & ~(size_t)255;
    return q;
  };
  unsigned short* pk_lin  = (unsigned short*)take(32  * 128 * 2);
  unsigned short* pk_e0w1 = (unsigned short*)take(128 * 256 * 2);
  unsigned short* pk_e0w2 = (unsigned short*)take(256 * 128 * 2);
  unsigned short* pk_e1w1 = (unsigned short*)take(128 * 256 * 2);
  unsigned short* pk_e1w2 = (unsigned short*)take(256 * 128 * 2);
  unsigned short* pk_kw   = (unsigned short*)take(128 * 128 * 2);
  unsigned short* pk_tw1  = (unsigned short*)take(128 * 256 * 2);
  unsigned short* pk_tw2  = (unsigned short*)take(256 * 128 * 2);
  float*  ck      = (float*)take((size_t)Npad * D_MAIN * sizeof(float));
  unsigned short* ckbf = (unsigned short*)take((size_t)Npad * D_MAIN * sizeof(unsigned short));
  float*  cknorm  = (float*)take((size_t)N * sizeof(float));
  float*  xh      = (float*)take((size_t)B * D_MAIN * sizeof(float));
  float*  xk      = (float*)take((size_t)B * D_MAIN * sizeof(float));
  __half* S       = (__half*)take((size_t)B * Npad * sizeof(__half));
  int*    ctxidx  = (int*)take((size_t)B * CTX * sizeof(int));
  int*    ghist   = (int*)take((size_t)B * TK_RBINS * sizeof(int));
  int*    thr     = (int*)take((size_t)B * sizeof(int));
  int*    scount  = (int*)take((size_t)B * sizeof(int));
  unsigned long long* surv =
      (unsigned long long*)take((size_t)B * TK_SCAP * sizeof(unsigned long long));
  (void)ws_size; (void)n_in; (void)out_size;

  auto packW = [&](const float* W, int K, int Nn, unsigned short* o) {
    const int total = (Nn / 16) * (K / 32) * 64;
    pack_w_kernel<<<(total + 255) / 256, 256, 0, stream>>>(W, K, Nn, o);
  };
  packW(lin_W, 32, 128, pk_lin);
  packW(e0_W1, 128, 256, pk_e0w1);
  packW(e0_W2, 256, 128, pk_e0w2);
  packW(e1_W1, 128, 256, pk_e1w1);
  packW(e1_W2, 256, 128, pk_e1w2);
  packW(K_W, 128, 128, pk_kw);
  packW(T_W1, 128, 256, pk_tw1);
  packW(T_W2, 256, 128, pk_tw2);

  {
    const int nz1 = B * TK_RBINS;
    zero_int_kernel<<<(nz1 + 255) / 256, 256, 0, stream>>>(ghist, nz1);
    zero_int_kernel<<<1, 256, 0, stream>>>(scount, B);
  }

  const int encC = (N + 127) / 128;
  encode_mfma<false><<<encC, 256, 0, stream>>>(
      cand_x, N, pk_lin, lin_b, pk_e0w1, e0_b1, pk_e0w2, e0_b2,
      e1_g, e1_b, pk_e1w1, e1_b1, pk_e1w2, e1_b2,
      mix_g, mix_b, pk_kw, K_b, ck, cknorm, nullptr, ckbf);

  const int encB = (B + 127) / 128;
  encode_mfma<true><<<encB, 256, 0, stream>>>(
      x_num, B, pk_lin, lin_b, pk_e0w1, e0_b1, pk_e0w2, e0_b2,
      e1_g, e1_b, pk_e1w1, e1_b1, pk_e1w2, e1_b2,
      mix_g, mix_b, pk_kw, K_b, xk, nullptr, xh, nullptr);

  dim3 sg(Npad / 256, B / 64);
  score_mfma<<<sg, 256, 0, stream>>>(xk, ckbf, cknorm, N, Npad, S);

  dim3 tg(chunks, B);
  thist_kernel<<<tg, 256, 0, stream>>>(S, Npad, ghist);
  tthresh_kernel<<<B, 256, 0, stream>>>(ghist, thr);
  tcollect_kernel<<<tg, 256, 0, stream>>>(S, Npad, thr, scount, surv);
  tsort_kernel<<<B, 1024, 0, stream>>>(surv, scount, ctxidx);

  tmod_kernel<<<B, 256, 0, stream>>>(
      xh, xk, ck, cand_y, ctxidx,
      pk_tw1, T_b1, pk_tw2, lab_w, lab_b,
      p0_g, p0_b, p0_W1, p0_b1, p0_W2, p0_b2,
      head_g, head_b, head_W, head_bias, out);
}

// Round 9
// 553.229 us; speedup vs baseline: 1.1818x; 1.0280x over previous
//
#include <hip/hip_runtime.h>
#include <hip/hip_fp16.h>
#include <float.h>
#include <math.h>

#define D_IN 32
#define D_MAIN 128
#define D_BLOCK 256
#define CTX 96
#define LN_EPS 1e-5f

typedef short bf16x8 __attribute__((ext_vector_type(8)));
typedef float f32x4 __attribute__((ext_vector_type(4)));
typedef unsigned short ushort4v __attribute__((ext_vector_type(4)));

#define LDA 136   // As stride (shorts), 272B rows; 68 dwords -> 2-way banks
#define LDJ 72    // u-scratch stride (shorts), 144B rows
#define LDF 68    // As-as-float stride (floats) == LDA/2

__device__ __forceinline__ unsigned short f2bf(float x) {
  union { float f; unsigned u; } v; v.f = x;
  const unsigned r = (v.u + 0x7FFFu + ((v.u >> 16) & 1u)) >> 16;
  return (unsigned short)r;
}
__device__ __forceinline__ unsigned pk2bf(float a, float b) {
  return (unsigned)f2bf(a) | ((unsigned)f2bf(b) << 16);
}

// ---------------------------------------------------------------------------
// Weight packing into MFMA fragment order (bf16); operand-symmetric layout.
// ---------------------------------------------------------------------------
__device__ __forceinline__ void packone(
    const float* __restrict__ W, int K, int N, unsigned short* __restrict__ out,
    int tid)
{
  const int ks = K / 32;
  const int l = tid & 63, f = tid >> 6;
  const int s = f % ks, j = f / ks;
  const int kb = s * 32 + (l >> 4) * 8;
  const int n = j * 16 + (l & 15);
  unsigned short v[8];
#pragma unroll
  for (int jj = 0; jj < 8; ++jj) v[jj] = f2bf(W[(size_t)(kb + jj) * N + n]);
  ushort4v* o = (ushort4v*)(out + (size_t)tid * 8);
  ushort4v u0 = {v[0], v[1], v[2], v[3]};
  ushort4v u1 = {v[4], v[5], v[6], v[7]};
  o[0] = u0; o[1] = u1;
}

// One launch: pack all 8 weights + zero ghist/scount.
__global__ __launch_bounds__(256) void prep_kernel(
    const float* __restrict__ lin_W, const float* __restrict__ e0_W1,
    const float* __restrict__ e0_W2, const float* __restrict__ e1_W1,
    const float* __restrict__ e1_W2, const float* __restrict__ K_W,
    const float* __restrict__ T_W1, const float* __restrict__ T_W2,
    unsigned short* __restrict__ pk_lin, unsigned short* __restrict__ pk_e0w1,
    unsigned short* __restrict__ pk_e0w2, unsigned short* __restrict__ pk_e1w1,
    unsigned short* __restrict__ pk_e1w2, unsigned short* __restrict__ pk_kw,
    unsigned short* __restrict__ pk_tw1, unsigned short* __restrict__ pk_tw2,
    int* __restrict__ ghist, int nghist, int* __restrict__ scount, int nsc)
{
  int tid = blockIdx.x * 256 + threadIdx.x;
  if (tid < 512)  { packone(lin_W, 32, 128, pk_lin, tid); return; }  tid -= 512;
  if (tid < 4096) { packone(e0_W1, 128, 256, pk_e0w1, tid); return; } tid -= 4096;
  if (tid < 4096) { packone(e0_W2, 256, 128, pk_e0w2, tid); return; } tid -= 4096;
  if (tid < 4096) { packone(e1_W1, 128, 256, pk_e1w1, tid); return; } tid -= 4096;
  if (tid < 4096) { packone(e1_W2, 256, 128, pk_e1w2, tid); return; } tid -= 4096;
  if (tid < 2048) { packone(K_W, 128, 128, pk_kw, tid); return; }    tid -= 2048;
  if (tid < 4096) { packone(T_W1, 128, 256, pk_tw1, tid); return; }  tid -= 4096;
  if (tid < 4096) { packone(T_W2, 256, 128, pk_tw2, tid); return; }  tid -= 4096;
  if (tid < nghist) { ghist[tid] = 0; return; }                      tid -= nghist;
  if (tid < nsc) scount[tid] = 0;
}
#define PREP_PACK_THREADS (512 + 4096*4 + 2048 + 4096*2)

// ---------------------------------------------------------------------------
// Wave-private MFMA MLP (M m-tiles of 16 rows): h += relu(As@W1+b1)@W2.
// Zero barriers; biases read from global (L2-resident).
// ---------------------------------------------------------------------------
template<int M>
__device__ __forceinline__ void mlp_reg(
    f32x4 (&h)[M][8],
    const unsigned short* __restrict__ As,
    unsigned short* __restrict__ Usw,
    const unsigned short* __restrict__ W1_pk,
    const float* __restrict__ b1,
    const unsigned short* __restrict__ W2_pk,
    int rbase, int c, int q, int lane)
{
#pragma unroll 1
  for (int jc = 0; jc < 4; ++jc) {
    f32x4 acc[4][M];
#pragma unroll
    for (int jt = 0; jt < 4; ++jt)
#pragma unroll
      for (int m = 0; m < M; ++m) { f32x4 z = {0.f,0.f,0.f,0.f}; acc[jt][m] = z; }
#pragma unroll
    for (int s = 0; s < 4; ++s) {
      bf16x8 bsrc[M];
#pragma unroll
      for (int m = 0; m < M; ++m)
        bsrc[m] = *(const bf16x8*)&As[(rbase + m*16 + c) * LDA + s*32 + q*8];
#pragma unroll
      for (int jt = 0; jt < 4; ++jt) {
        const bf16x8 wf = *(const bf16x8*)&W1_pk[((size_t)((jc*4+jt)*4 + s) * 64 + lane) * 8];
#pragma unroll
        for (int m = 0; m < M; ++m)
          acc[jt][m] = __builtin_amdgcn_mfma_f32_16x16x32_bf16(wf, bsrc[m], acc[jt][m], 0, 0, 0);
      }
    }
    // bias + relu + pack; u^T C-layout: regs hold j=q*4+r, lanes hold row=c
#pragma unroll
    for (int jt = 0; jt < 4; ++jt) {
      const int jb = (jc*4 + jt) * 16 + q*4;
      const float bv0 = b1[jb + 0];
      const float bv1 = b1[jb + 1];
      const float bv2 = b1[jb + 2];
      const float bv3 = b1[jb + 3];
#pragma unroll
      for (int m = 0; m < M; ++m) {
        uint2 dd;
        dd.x = pk2bf(fmaxf(acc[jt][m][0] + bv0, 0.f), fmaxf(acc[jt][m][1] + bv1, 0.f));
        dd.y = pk2bf(fmaxf(acc[jt][m][2] + bv2, 0.f), fmaxf(acc[jt][m][3] + bv3, 0.f));
        *(uint2*)&Usw[(m*16 + c) * LDJ + jt*16 + q*4] = dd;
      }
    }
    __threadfence_block();
    // phase B: h += u @ W2 (k-chunk jc*64..+64)
#pragma unroll
    for (int kw = 0; kw < 2; ++kw) {
      bf16x8 af[M];
#pragma unroll
      for (int m = 0; m < M; ++m)
        af[m] = *(const bf16x8*)&Usw[(m*16 + c) * LDJ + kw*32 + q*8];
#pragma unroll
      for (int nt = 0; nt < 8; ++nt) {
        const bf16x8 bw = *(const bf16x8*)&W2_pk[((size_t)(nt*8 + jc*2 + kw) * 64 + lane) * 8];
#pragma unroll
        for (int m = 0; m < M; ++m)
          h[m][nt] = __builtin_amdgcn_mfma_f32_16x16x32_bf16(af[m], bw, h[m][nt], 0, 0, 0);
      }
    }
  }
}

// LN over register h, write normalized bf16 to As (wave-private rows).
template<int M>
__device__ __forceinline__ void ln_write(
    f32x4 (&h)[M][8], unsigned short* __restrict__ As,
    const float* __restrict__ g, const float* __restrict__ bv,
    int rbase, int c, int q)
{
  float mu[M][4], rs[M][4];
#pragma unroll
  for (int m = 0; m < M; ++m)
#pragma unroll
    for (int r = 0; r < 4; ++r) {
      float s = 0.f, ss = 0.f;
#pragma unroll
      for (int nt = 0; nt < 8; ++nt) { const float v = h[m][nt][r]; s += v; ss += v * v; }
#pragma unroll
      for (int off = 1; off < 16; off <<= 1) {
        s += __shfl_xor(s, off, 64);
        ss += __shfl_xor(ss, off, 64);
      }
      const float m_ = s * (1.f / 128.f);
      mu[m][r] = m_;
      rs[m][r] = rsqrtf(ss * (1.f / 128.f) - m_ * m_ + LN_EPS);
    }
#pragma unroll
  for (int nt = 0; nt < 8; ++nt) {
    const int col = nt*16 + c;
    const float gg = g[col], bb = bv[col];
#pragma unroll
    for (int m = 0; m < M; ++m)
#pragma unroll
      for (int r = 0; r < 4; ++r)
        As[(rbase + m*16 + q*4 + r) * LDA + col] =
            f2bf((h[m][nt][r] - mu[m][r]) * rs[m][r] * gg + bb);
  }
  __threadfence_block();
}

// ---------------------------------------------------------------------------
// Encoder: block = 64 rows, 4 waves, each wave owns 16 rows. One barrier.
// LDS 26.6 KB -> 6 blocks/CU (24 waves/CU) for latency hiding.
// ---------------------------------------------------------------------------
template<bool QUERY>
__global__ __launch_bounds__(256, 6) void encode_mfma(
    const float* __restrict__ xin, int nrows,
    const unsigned short* __restrict__ linW_pk, const float* __restrict__ lin_b,
    const unsigned short* __restrict__ e0W1_pk, const float* __restrict__ e0_b1,
    const unsigned short* __restrict__ e0W2_pk, const float* __restrict__ e0_b2,
    const float* __restrict__ e1_g, const float* __restrict__ e1_b,
    const unsigned short* __restrict__ e1W1_pk, const float* __restrict__ e1_b1,
    const unsigned short* __restrict__ e1W2_pk, const float* __restrict__ e1_b2,
    const float* __restrict__ mix_g, const float* __restrict__ mix_b,
    const unsigned short* __restrict__ KW_pk, const float* __restrict__ K_b,
    float* __restrict__ k_out, float* __restrict__ knorm_out,
    float* __restrict__ h_out, unsigned short* __restrict__ ckbf_out)
{
  __shared__ unsigned short As[64 * LDA];
  __shared__ unsigned short Usw[4][16 * LDJ];
  const int t = threadIdx.x, lane = t & 63, w = t >> 6;
  const int c = lane & 15, q = lane >> 4;
  const int rbase = w * 16;
  const int row0 = blockIdx.x * 64;

  for (int i = t; i < 64 * 8; i += 256) {
    const int r = i >> 3, c4 = (i & 7) * 4;
    const int gr = row0 + r;
    float4 v = make_float4(0.f, 0.f, 0.f, 0.f);
    if (gr < nrows) v = *(const float4*)&xin[(size_t)gr * D_IN + c4];
    ushort4v u = {f2bf(v.x), f2bf(v.y), f2bf(v.z), f2bf(v.w)};
    *(ushort4v*)&As[r * LDA + c4] = u;
  }
  __syncthreads();

  f32x4 h[1][8];
  { // input linear (K=32)
    const bf16x8 a = *(const bf16x8*)&As[(rbase + c) * LDA + q*8];
#pragma unroll
    for (int nt = 0; nt < 8; ++nt) {
      const bf16x8 bw = *(const bf16x8*)&linW_pk[((size_t)nt * 64 + lane) * 8];
      const float bb = lin_b[nt*16 + c];
      f32x4 z = {0.f, 0.f, 0.f, 0.f};
      z = __builtin_amdgcn_mfma_f32_16x16x32_bf16(a, bw, z, 0, 0, 0);
      z[0] += bb; z[1] += bb; z[2] += bb; z[3] += bb;
      h[0][nt] = z;
    }
  }
  // h -> As (e0 input), wave-private rows
#pragma unroll
  for (int nt = 0; nt < 8; ++nt)
#pragma unroll
    for (int r = 0; r < 4; ++r)
      As[(rbase + q*4 + r) * LDA + nt*16 + c] = f2bf(h[0][nt][r]);
  __threadfence_block();

  mlp_reg<1>(h, As, Usw[w], e0W1_pk, e0_b1, e0W2_pk, rbase, c, q, lane);
#pragma unroll
  for (int nt = 0; nt < 8; ++nt) {
    const float bb = e0_b2[nt*16 + c];
    h[0][nt][0] += bb; h[0][nt][1] += bb; h[0][nt][2] += bb; h[0][nt][3] += bb;
  }

  ln_write<1>(h, As, e1_g, e1_b, rbase, c, q);
  mlp_reg<1>(h, As, Usw[w], e1W1_pk, e1_b1, e1W2_pk, rbase, c, q, lane);
#pragma unroll
  for (int nt = 0; nt < 8; ++nt) {
    const float bb = e1_b2[nt*16 + c];
    h[0][nt][0] += bb; h[0][nt][1] += bb; h[0][nt][2] += bb; h[0][nt][3] += bb;
  }

  ln_write<1>(h, As, mix_g, mix_b, rbase, c, q);
  // h dead in candidate path from here.

  // K projection
  f32x4 kk[8];
#pragma unroll
  for (int nt = 0; nt < 8; ++nt) { f32x4 z = {0.f,0.f,0.f,0.f}; kk[nt] = z; }
#pragma unroll
  for (int s = 0; s < 4; ++s) {
    const bf16x8 a = *(const bf16x8*)&As[(rbase + c) * LDA + s*32 + q*8];
#pragma unroll
    for (int nt = 0; nt < 8; ++nt) {
      const bf16x8 bw = *(const bf16x8*)&KW_pk[((size_t)(nt*4 + s) * 64 + lane) * 8];
      kk[nt] = __builtin_amdgcn_mfma_f32_16x16x32_bf16(a, bw, kk[nt], 0, 0, 0);
    }
  }
#pragma unroll
  for (int nt = 0; nt < 8; ++nt) {
    const float bb = K_b[nt*16 + c];
    kk[nt][0] += bb; kk[nt][1] += bb; kk[nt][2] += bb; kk[nt][3] += bb;
  }

  if constexpr (QUERY) {
#pragma unroll
    for (int nt = 0; nt < 8; ++nt) {
      const int col = nt*16 + c;
#pragma unroll
      for (int r = 0; r < 4; ++r) {
        const int gr = row0 + rbase + q*4 + r;
        if (gr < nrows) {
          k_out[(size_t)gr * D_MAIN + col] = kk[nt][r];
          h_out[(size_t)gr * D_MAIN + col] = h[0][nt][r];
        }
      }
    }
  } else {
    // knorm (shuffle-reduced per row)
#pragma unroll
    for (int r = 0; r < 4; ++r) {
      float ss = 0.f;
#pragma unroll
      for (int nt = 0; nt < 8; ++nt) { const float v = kk[nt][r]; ss += v * v; }
#pragma unroll
      for (int off = 1; off < 16; off <<= 1) ss += __shfl_xor(ss, off, 64);
      const int gr = row0 + rbase + q*4 + r;
      if (c == 0 && gr < nrows) knorm_out[gr] = ss;
    }
    // wave-private two-pass restage (16 x 64 floats per pass, stride LDF)
    float* Asf = (float*)&As[rbase * LDA];
#pragma unroll 1
    for (int p = 0; p < 2; ++p) {
      if (p) __threadfence_block();   // WAR: pass-0 reads vs pass-1 writes
#pragma unroll
      for (int j = 0; j < 4; ++j) {
        const int nt = p*4 + j;
#pragma unroll
        for (int r = 0; r < 4; ++r)
          Asf[(q*4 + r) * LDF + j*16 + c] = kk[nt][r];
      }
      __threadfence_block();
#pragma unroll
      for (int i = 0; i < 4; ++i) {
        const int flat = i * 64 + lane;     // 0..255
        const int row = flat >> 4;          // 0..15
        const int fc = (flat & 15) * 4;     // 0..60
        const int gr = row0 + rbase + row;
        if (gr < nrows) {
          const float4 v = *(const float4*)&Asf[row * LDF + fc];
          *(float4*)&k_out[(size_t)gr * D_MAIN + p*64 + fc] = v;
          ushort4v u = {f2bf(v.x), f2bf(v.y), f2bf(v.z), f2bf(v.w)};
          *(ushort4v*)&ckbf_out[(size_t)gr * D_MAIN + p*64 + fc] = u;
        }
      }
    }
  }
}

// ---------------------------------------------------------------------------
// Score: S[b][j] = 2*dot(xk[b], ck[j]) - ||ck[j]||^2, fp16.
// ---------------------------------------------------------------------------
__global__ __launch_bounds__(256) void score_mfma(
    const float* __restrict__ xk, const unsigned short* __restrict__ ckbf,
    const float* __restrict__ cknorm, int N, int Npad,
    __half* __restrict__ S)
{
  __shared__ unsigned short Ks[64 * 136];
  const int t = threadIdx.x, lane = t & 63, w = t >> 6;
  const int c = lane & 15, q = lane >> 4;
  const int b0 = blockIdx.y * 64;
  const int n0 = blockIdx.x * 256 + w * 64;

  for (int i = t; i < 64 * 32; i += 256) {
    const int r = i >> 5, c4 = (i & 31) * 4;
    const float4 v = *(const float4*)&xk[(size_t)(b0 + r) * D_MAIN + c4];
    ushort4v u = {f2bf(v.x), f2bf(v.y), f2bf(v.z), f2bf(v.w)};
    *(ushort4v*)&Ks[r * 136 + c4] = u;
  }
  __syncthreads();

  f32x4 acc[4][4];
#pragma unroll
  for (int mi = 0; mi < 4; ++mi)
#pragma unroll
    for (int nt = 0; nt < 4; ++nt) { f32x4 z = {0.f,0.f,0.f,0.f}; acc[mi][nt] = z; }

#pragma unroll 1
  for (int s = 0; s < 4; ++s) {
    bf16x8 a[4];
#pragma unroll
    for (int mi = 0; mi < 4; ++mi)
      a[mi] = *(const bf16x8*)&Ks[(mi*16 + c) * 136 + s*32 + q*8];
#pragma unroll
    for (int nt = 0; nt < 4; ++nt) {
      const size_t n = (size_t)(n0 + nt*16 + c);
      const bf16x8 b = *(const bf16x8*)&ckbf[n * D_MAIN + s*32 + q*8];
#pragma unroll
      for (int mi = 0; mi < 4; ++mi)
        acc[mi][nt] = __builtin_amdgcn_mfma_f32_16x16x32_bf16(a[mi], b, acc[mi][nt], 0, 0, 0);
    }
  }
#pragma unroll
  for (int nt = 0; nt < 4; ++nt) {
    const int col = n0 + nt*16 + c;
    const float cn = (col < N) ? cknorm[col] : 0.f;
#pragma unroll
    for (int mi = 0; mi < 4; ++mi)
#pragma unroll
      for (int r = 0; r < 4; ++r) {
        const int row = b0 + mi*16 + q*4 + r;
        const float sv = (col < N) ? (2.f * acc[mi][nt][r] - cn) : -65504.f;
        S[(size_t)row * Npad + col] = __float2half(sv);
      }
  }
}

// ---------------------------------------------------------------------------
// Parallel radix-threshold top-K.
// ---------------------------------------------------------------------------
#define TK_CHUNK 4096
#define TK_RBINS 4096
#define TK_SCAP 2048

__device__ __forceinline__ unsigned flip2(unsigned u) {
  const unsigned m = (u >> 15) & 0x00010001u;
  const unsigned xm = (m * 0xFFFFu) | ((m ^ 0x00010001u) * 0x8000u);
  return u ^ xm;
}

__global__ __launch_bounds__(256) void thist_kernel(
    const __half* __restrict__ S, int Npad, int* __restrict__ ghist)
{
  __shared__ int lh[TK_RBINS];
  const int t = threadIdx.x;
  const int row = blockIdx.y;
  const int c0 = blockIdx.x * TK_CHUNK;
  for (int i = t; i < TK_RBINS; i += 256) lh[i] = 0;
  __syncthreads();
  const unsigned* rp = (const unsigned*)(S + (size_t)row * Npad);
#pragma unroll
  for (int half = 0; half < 2; ++half) {
    const int j = c0 + half * 2048 + t * 8;
    if (j < Npad) {
      const uint4 v = *(const uint4*)(rp + (j >> 1));
      const unsigned k0 = flip2(v.x), k1 = flip2(v.y);
      const unsigned k2 = flip2(v.z), k3 = flip2(v.w);
      atomicAdd(&lh[(k0 & 0xFFFFu) >> 4], 1); atomicAdd(&lh[k0 >> 20], 1);
      atomicAdd(&lh[(k1 & 0xFFFFu) >> 4], 1); atomicAdd(&lh[k1 >> 20], 1);
      atomicAdd(&lh[(k2 & 0xFFFFu) >> 4], 1); atomicAdd(&lh[k2 >> 20], 1);
      atomicAdd(&lh[(k3 & 0xFFFFu) >> 4], 1); atomicAdd(&lh[k3 >> 20], 1);
    }
  }
  __syncthreads();
  int* gh = ghist + (size_t)row * TK_RBINS;
  for (int i = t; i < TK_RBINS; i += 256) {
    const int v = lh[i];
    if (v) atomicAdd(&gh[i], v);
  }
}

__global__ __launch_bounds__(256) void tthresh_kernel(
    const int* __restrict__ ghist, int* __restrict__ thr)
{
  __shared__ int sp[257];
  const int t = threadIdx.x;
  const int row = blockIdx.x;
  const int* gh = ghist + (size_t)row * TK_RBINS;
  int s = 0;
#pragma unroll
  for (int i = 0; i < 16; ++i) s += gh[t * 16 + i];
  sp[t] = s;
  if (t == 0) sp[256] = 0;
  __syncthreads();
  for (int off = 1; off < 256; off <<= 1) {
    const int v = (t + off < 256) ? sp[t + off] : 0;
    __syncthreads();
    sp[t] += v;
    __syncthreads();
  }
  if (sp[t] >= CTX && (t == 255 || sp[t + 1] < CTX)) {
    int running = (t == 255) ? 0 : sp[t + 1];
    int T = t * 16;
    for (int b = t * 16 + 15; b >= t * 16; --b) {
      running += gh[b];
      if (running >= CTX) { T = b; break; }
    }
    thr[row] = T;
  }
}

__global__ __launch_bounds__(256) void tcollect_kernel(
    const __half* __restrict__ S, int Npad, const int* __restrict__ thr,
    int* __restrict__ scount, unsigned long long* __restrict__ surv)
{
  const int t = threadIdx.x;
  const int row = blockIdx.y;
  const int c0 = blockIdx.x * TK_CHUNK;
  const int T = thr[row];
  const unsigned* rp = (const unsigned*)(S + (size_t)row * Npad);
  unsigned long long* sv = surv + (size_t)row * TK_SCAP;
#pragma unroll
  for (int half = 0; half < 2; ++half) {
    const int j = c0 + half * 2048 + t * 8;
    if (j < Npad) {
      const uint4 v = *(const uint4*)(rp + (j >> 1));
      unsigned ks[4] = {flip2(v.x), flip2(v.y), flip2(v.z), flip2(v.w)};
#pragma unroll
      for (int wqi = 0; wqi < 4; ++wqi) {
        const unsigned klo = ks[wqi] & 0xFFFFu;
        const unsigned khi = ks[wqi] >> 16;
        const int jlo = j + wqi * 2, jhi = j + wqi * 2 + 1;
        if ((int)(klo >> 4) >= T) {
          const int pos = atomicAdd(&scount[row], 1);
          if (pos < TK_SCAP)
            sv[pos] = ((unsigned long long)klo << 32) | (0xFFFFFFFFu - (unsigned)jlo);
        }
        if ((int)(khi >> 4) >= T) {
          const int pos = atomicAdd(&scount[row], 1);
          if (pos < TK_SCAP)
            sv[pos] = ((unsigned long long)khi << 32) | (0xFFFFFFFFu - (unsigned)jhi);
        }
      }
    }
  }
}

__global__ __launch_bounds__(1024) void tsort_kernel(
    const unsigned long long* __restrict__ surv, const int* __restrict__ scount,
    int* __restrict__ idx_out)
{
  __shared__ unsigned long long sb[TK_SCAP];
  const int t = threadIdx.x;
  const int row = blockIdx.x;
  const int m = min(scount[row], TK_SCAP);
  int L = 128;
  while (L < m) L <<= 1;
  const unsigned long long* sv = surv + (size_t)row * TK_SCAP;
  for (int i = t; i < L; i += 1024)
    sb[i] = (i < m) ? sv[i] : 0x00000000FFFFFFFFull;
  __syncthreads();
  for (int k = 2; k <= L; k <<= 1) {
    for (int j = k >> 1; j > 0; j >>= 1) {
      for (int i = t; i < L; i += 1024) {
        const int ixj = i ^ j;
        if (ixj > i) {
          const unsigned long long a = sb[i], b = sb[ixj];
          const bool desc = ((i & k) == 0);
          if ((a < b) == desc) { sb[i] = b; sb[ixj] = a; }
        }
      }
      __syncthreads();
    }
  }
  if (t < CTX)
    idx_out[row * CTX + t] = (int)(0xFFFFFFFFu - (unsigned)(sb[t] & 0xFFFFFFFFu));
}

// ---------------------------------------------------------------------------
// T-module + predictor + head. One block per query, 4 waves, mlp_reg<2>.
// ---------------------------------------------------------------------------
__global__ __launch_bounds__(256, 2) void tmod_kernel(
    const float* __restrict__ xh, const float* __restrict__ xk,
    const float* __restrict__ ck, const float* __restrict__ cand_y,
    const int* __restrict__ ctx_idx,
    const unsigned short* __restrict__ TW1_pk, const float* __restrict__ T_b1,
    const unsigned short* __restrict__ TW2_pk,
    const float* __restrict__ lab_w, const float* __restrict__ lab_b,
    const float* __restrict__ p0_g, const float* __restrict__ p0_b,
    const float* __restrict__ p0_W1, const float* __restrict__ p0_b1,
    const float* __restrict__ p0_W2, const float* __restrict__ p0_b2,
    const float* __restrict__ head_g, const float* __restrict__ head_b,
    const float* __restrict__ head_W, const float* __restrict__ head_bias,
    float* __restrict__ out)
{
  __shared__ unsigned short As[128 * LDA];
  __shared__ unsigned short Usw[4][32 * LDJ];
  __shared__ float kb[128], xhs[128], probs[128], sims[128], ys[128];
  __shared__ float part[4][128];
  __shared__ int idxs[128];
  __shared__ float xr[128], dl[128], ubuf[256], vbuf[256], scal[4];
  const int t = threadIdx.x, lane = t & 63, w = t >> 6;
  const int c = lane & 15, q = lane >> 4;
  const int rbase = w * 32;
  const int b = blockIdx.x;
  float* spart = (float*)&Usw[0][0];   // [128][16] overlay, used pre-MLP only

  if (t < 128) {
    ys[t] = 0.f;
    if (t < CTX) {
      const int j = ctx_idx[b * CTX + t];
      idxs[t] = j;
      ys[t] = cand_y[j];
    }
  }
  if (t < 32) {
    *(float4*)&kb[t * 4] = *(const float4*)&xk[(size_t)b * D_MAIN + t * 4];
  } else if (t < 64) {
    const int i = t - 32;
    *(float4*)&xhs[i * 4] = *(const float4*)&xh[(size_t)b * D_MAIN + i * 4];
  }
  __syncthreads();

  for (int i = t; i < 128 * 16; i += 256) {
    const int r = i >> 4, seg = i & 15, c0 = seg * 8;
    if (r < CTX) {
      const float* cr = &ck[(size_t)idxs[r] * D_MAIN + c0];
      const float4 v0 = *(const float4*)cr;
      const float4 v1 = *(const float4*)(cr + 4);
      const float4 k0 = *(const float4*)&kb[c0];
      const float4 k1 = *(const float4*)&kb[c0 + 4];
      const float d0 = k0.x - v0.x, d1 = k0.y - v0.y, d2 = k0.z - v0.z, d3 = k0.w - v0.w;
      const float d4 = k1.x - v1.x, d5 = k1.y - v1.y, d6 = k1.z - v1.z, d7 = k1.w - v1.w;
      ushort4v u0 = {f2bf(d0), f2bf(d1), f2bf(d2), f2bf(d3)};
      ushort4v u1 = {f2bf(d4), f2bf(d5), f2bf(d6), f2bf(d7)};
      *(ushort4v*)&As[r * LDA + c0] = u0;
      *(ushort4v*)&As[r * LDA + c0 + 4] = u1;
      spart[r * 16 + seg] = d0*d0 + d1*d1 + d2*d2 + d3*d3 + d4*d4 + d5*d5 + d6*d6 + d7*d7;
    } else {
      ushort4v z = {0, 0, 0, 0};
      *(ushort4v*)&As[r * LDA + c0] = z;
      *(ushort4v*)&As[r * LDA + c0 + 4] = z;
    }
  }
  __syncthreads();
  if (t < 128) {
    float s = 0.f;
    if (t < CTX) {
#pragma unroll
      for (int seg = 0; seg < 16; ++seg) s += spart[t * 16 + seg];
      sims[t] = -s;
    } else {
      sims[t] = -FLT_MAX;
    }
  }
  __syncthreads();
  if (t < 64) {
    float m = fmaxf(sims[t], sims[t + 64]);
#pragma unroll
    for (int off = 32; off > 0; off >>= 1) m = fmaxf(m, __shfl_xor(m, off, 64));
    if (t == 0) scal[0] = m;
  }
  __syncthreads();
  if (t < 128) probs[t] = (t < CTX) ? __expf(sims[t] - scal[0]) : 0.f;
  __syncthreads();
  if (t < 64) {
    float s = probs[t] + probs[t + 64];
#pragma unroll
    for (int off = 32; off > 0; off >>= 1) s += __shfl_xor(s, off, 64);
    if (t == 0) scal[1] = 1.f / s;
  }
  __syncthreads();
  if (t < 128) probs[t] *= scal[1];
  __syncthreads();
  if (t < 64) {
    float sy = probs[t] * ys[t] + probs[t + 64] * ys[t + 64];
#pragma unroll
    for (int off = 32; off > 0; off >>= 1) sy += __shfl_xor(sy, off, 64);
    if (t == 0) scal[2] = sy;
  }
  __syncthreads();   // spart reads done; Usw free for mlp_reg

  f32x4 h[2][8];
#pragma unroll
  for (int m = 0; m < 2; ++m)
#pragma unroll
    for (int nt = 0; nt < 8; ++nt) { f32x4 z = {0.f,0.f,0.f,0.f}; h[m][nt] = z; }
  mlp_reg<2>(h, As, Usw[w], TW1_pk, T_b1, TW2_pk, rbase, c, q, lane);

  // ctx[col] = sum_rows probs[row] * h[row][col]
  float pr[2][4];
#pragma unroll
  for (int m = 0; m < 2; ++m)
#pragma unroll
    for (int r = 0; r < 4; ++r)
      pr[m][r] = probs[rbase + m*16 + q*4 + r];
#pragma unroll
  for (int nt = 0; nt < 8; ++nt) {
    float p = 0.f;
#pragma unroll
    for (int m = 0; m < 2; ++m)
#pragma unroll
      for (int r = 0; r < 4; ++r)
        p += pr[m][r] * h[m][nt][r];
    p += __shfl_xor(p, 16, 64);
    p += __shfl_xor(p, 32, 64);
    if (lane < 16) part[w][nt*16 + c] = p;
  }
  __syncthreads();

  if (t < 128)
    xr[t] = xhs[t] + part[0][t] + part[1][t] + part[2][t] + part[3][t]
          + scal[2] * lab_w[t] + lab_b[t];
  __syncthreads();
  if (t < 64) {
    float s = xr[t] + xr[t + 64];
    float ss = xr[t]*xr[t] + xr[t+64]*xr[t+64];
#pragma unroll
    for (int off = 32; off > 0; off >>= 1) {
      s += __shfl_xor(s, off, 64);
      ss += __shfl_xor(ss, off, 64);
    }
    if (t == 0) {
      const float mu = s * (1.f / 128.f);
      scal[0] = mu;
      scal[1] = rsqrtf(ss * (1.f / 128.f) - mu * mu + LN_EPS);
    }
  }
  __syncthreads();
  if (t < 128)
    dl[t] = (xr[t] - scal[0]) * scal[1] * p0_g[t] + p0_b[t];
  __syncthreads();
  {
    float u = 0.f;
    for (int cc = 0; cc < D_MAIN; cc += 4) {
      const float w0 = p0_W1[(cc + 0) * D_BLOCK + t];
      const float w1 = p0_W1[(cc + 1) * D_BLOCK + t];
      const float w2 = p0_W1[(cc + 2) * D_BLOCK + t];
      const float w3 = p0_W1[(cc + 3) * D_BLOCK + t];
      const float4 d4 = *(const float4*)&dl[cc];
      u += d4.x * w0 + d4.y * w1 + d4.z * w2 + d4.w * w3;
    }
    ubuf[t] = fmaxf(u + p0_b1[t], 0.f);
  }
  __syncthreads();
  {
    const int cc = t & 127;
    const int d0 = (t >> 7) * 128;
    float v = 0.f;
    for (int d = d0; d < d0 + 128; d += 4) {
      const float w0 = p0_W2[(d + 0) * D_MAIN + cc];
      const float w1 = p0_W2[(d + 1) * D_MAIN + cc];
      const float w2 = p0_W2[(d + 2) * D_MAIN + cc];
      const float w3 = p0_W2[(d + 3) * D_MAIN + cc];
      const float4 u4 = *(const float4*)&ubuf[d];
      v += u4.x * w0 + u4.y * w1 + u4.z * w2 + u4.w * w3;
    }
    vbuf[t] = v;
  }
  __syncthreads();
  if (t < 128) xr[t] += vbuf[t] + vbuf[t + 128] + p0_b2[t];
  __syncthreads();
  if (t < 64) {
    float s = xr[t] + xr[t + 64];
    float ss = xr[t]*xr[t] + xr[t+64]*xr[t+64];
#pragma unroll
    for (int off = 32; off > 0; off >>= 1) {
      s += __shfl_xor(s, off, 64);
      ss += __shfl_xor(ss, off, 64);
    }
    if (t == 0) {
      const float mu = s * (1.f / 128.f);
      scal[0] = mu;
      scal[1] = rsqrtf(ss * (1.f / 128.f) - mu * mu + LN_EPS);
    }
  }
  __syncthreads();
  if (t < 128) {
    float hv = (xr[t] - scal[0]) * scal[1] * head_g[t] + head_b[t];
    dl[t] = fmaxf(hv, 0.f) * head_W[t];
  }
  __syncthreads();
  if (t < 64) {
    float s = dl[t] + dl[t + 64];
#pragma unroll
    for (int off = 32; off > 0; off >>= 1) s += __shfl_xor(s, off, 64);
    if (t == 0) out[b] = s + head_bias[0];
  }
}

// ---------------------------------------------------------------------------
extern "C" void kernel_launch(void* const* d_in, const int* in_sizes, int n_in,
                              void* d_out, int out_size, void* d_ws, size_t ws_size,
                              hipStream_t stream)
{
  const float* x_num   = (const float*)d_in[0];
  const float* cand_x  = (const float*)d_in[1];
  const float* cand_y  = (const float*)d_in[2];
  const float* lin_W   = (const float*)d_in[4];
  const float* lin_b   = (const float*)d_in[5];
  const float* e0_W1   = (const float*)d_in[6];
  const float* e0_b1   = (const float*)d_in[7];
  const float* e0_W2   = (const float*)d_in[8];
  const float* e0_b2   = (const float*)d_in[9];
  const float* e1_g    = (const float*)d_in[10];
  const float* e1_b    = (const float*)d_in[11];
  const float* e1_W1   = (const float*)d_in[12];
  const float* e1_b1   = (const float*)d_in[13];
  const float* e1_W2   = (const float*)d_in[14];
  const float* e1_b2   = (const float*)d_in[15];
  const float* mix_g   = (const float*)d_in[16];
  const float* mix_b   = (const float*)d_in[17];
  const float* K_W     = (const float*)d_in[18];
  const float* K_b     = (const float*)d_in[19];
  const float* T_W1    = (const float*)d_in[20];
  const float* T_b1    = (const float*)d_in[21];
  const float* T_W2    = (const float*)d_in[22];
  const float* lab_w   = (const float*)d_in[23];
  const float* lab_b   = (const float*)d_in[24];
  const float* p0_g    = (const float*)d_in[25];
  const float* p0_b    = (const float*)d_in[26];
  const float* p0_W1   = (const float*)d_in[27];
  const float* p0_b1   = (const float*)d_in[28];
  const float* p0_W2   = (const float*)d_in[29];
  const float* p0_b2   = (const float*)d_in[30];
  const float* head_g  = (const float*)d_in[31];
  const float* head_b  = (const float*)d_in[32];
  const float* head_W  = (const float*)d_in[33];
  const float* head_bias = (const float*)d_in[34];
  float* out = (float*)d_out;

  const int N = in_sizes[1] / D_IN;
  const int B = in_sizes[0] / D_IN;
  const int Npad = ((N + 255) / 256) * 256;
  const int chunks = (Npad + TK_CHUNK - 1) / TK_CHUNK;

  char* p = (char*)d_ws;
  auto take = [&](size_t bytes) {
    char* q = p;
    p += (bytes + 255) & ~(size_t)255;
    return q;
  };
  unsigned short* pk_lin  = (unsigned short*)take(32  * 128 * 2);
  unsigned short* pk_e0w1 = (unsigned short*)take(128 * 256 * 2);
  unsigned short* pk_e0w2 = (unsigned short*)take(256 * 128 * 2);
  unsigned short* pk_e1w1 = (unsigned short*)take(128 * 256 * 2);
  unsigned short* pk_e1w2 = (unsigned short*)take(256 * 128 * 2);
  unsigned short* pk_kw   = (unsigned short*)take(128 * 128 * 2);
  unsigned short* pk_tw1  = (unsigned short*)take(128 * 256 * 2);
  unsigned short* pk_tw2  = (unsigned short*)take(256 * 128 * 2);
  float*  ck      = (float*)take((size_t)Npad * D_MAIN * sizeof(float));
  unsigned short* ckbf = (unsigned short*)take((size_t)Npad * D_MAIN * sizeof(unsigned short));
  float*  cknorm  = (float*)take((size_t)N * sizeof(float));
  float*  xh      = (float*)take((size_t)B * D_MAIN * sizeof(float));
  float*  xk      = (float*)take((size_t)B * D_MAIN * sizeof(float));
  __half* S       = (__half*)take((size_t)B * Npad * sizeof(__half));
  int*    ctxidx  = (int*)take((size_t)B * CTX * sizeof(int));
  int*    ghist   = (int*)take((size_t)B * TK_RBINS * sizeof(int));
  int*    thr     = (int*)take((size_t)B * sizeof(int));
  int*    scount  = (int*)take((size_t)B * sizeof(int));
  unsigned long long* surv =
      (unsigned long long*)take((size_t)B * TK_SCAP * sizeof(unsigned long long));
  (void)ws_size; (void)n_in; (void)out_size;

  // one launch: pack all weights + zero ghist/scount
  {
    const int nghist = B * TK_RBINS;
    const long long total = (long long)PREP_PACK_THREADS + nghist + B;
    prep_kernel<<<(int)((total + 255) / 256), 256, 0, stream>>>(
        lin_W, e0_W1, e0_W2, e1_W1, e1_W2, K_W, T_W1, T_W2,
        pk_lin, pk_e0w1, pk_e0w2, pk_e1w1, pk_e1w2, pk_kw, pk_tw1, pk_tw2,
        ghist, nghist, scount, B);
  }

  const int encC = (N + 63) / 64;
  encode_mfma<false><<<encC, 256, 0, stream>>>(
      cand_x, N, pk_lin, lin_b, pk_e0w1, e0_b1, pk_e0w2, e0_b2,
      e1_g, e1_b, pk_e1w1, e1_b1, pk_e1w2, e1_b2,
      mix_g, mix_b, pk_kw, K_b, ck, cknorm, nullptr, ckbf);

  const int encB = (B + 63) / 64;
  encode_mfma<true><<<encB, 256, 0, stream>>>(
      x_num, B, pk_lin, lin_b, pk_e0w1, e0_b1, pk_e0w2, e0_b2,
      e1_g, e1_b, pk_e1w1, e1_b1, pk_e1w2, e1_b2,
      mix_g, mix_b, pk_kw, K_b, xk, nullptr, xh, nullptr);

  dim3 sg(Npad / 256, B / 64);
  score_mfma<<<sg, 256, 0, stream>>>(xk, ckbf, cknorm, N, Npad, S);

  dim3 tg(chunks, B);
  thist_kernel<<<tg, 256, 0, stream>>>(S, Npad, ghist);
  tthresh_kernel<<<B, 256, 0, stream>>>(ghist, thr);
  tcollect_kernel<<<tg, 256, 0, stream>>>(S, Npad, thr, scount, surv);
  tsort_kernel<<<B, 1024, 0, stream>>>(surv, scount, ctxidx);

  tmod_kernel<<<B, 256, 0, stream>>>(
      xh, xk, ck, cand_y, ctxidx,
      pk_tw1, T_b1, pk_tw2, lab_w, lab_b,
      p0_g, p0_b, p0_W1, p0_b1, p0_W2, p0_b2,
      head_g, head_b, head_W, head_bias, out);
}